// Round 1
// 656.453 us; speedup vs baseline: 1.0202x; 1.0202x over previous
//
#include <hip/hip_runtime.h>
#include <cstddef>
#include <cstdint>

// ---------------------------------------------------------------------------
// HGT forward for MI355X. C=128, H=8, D=16, OUT=64, L=2
//   NN = {30000, 60000, 6000}, NE = {200000, 300000, 200000, 100000}
//   ETS = {(0,1),(1,1),(1,2),(2,0)}
// Round-10 changes:
//  * attn_run: next-edge K/V software prefetch (loads independent of the
//    online-softmax chain) + defer-max (THR=8, T13): skip o-rescale unless
//    the running max grows by >8. agg_all was latency-bound: 42% HBM,
//    38% VALU, 42% occupancy at 65.5us.
//  * region section: 4-way edge split (was 2), chain ~17 -> ~8 trips.
//  * gemm_proj x3 fused into gemm_proj_all (one launch per layer).
// ---------------------------------------------------------------------------

typedef __attribute__((ext_vector_type(8))) short short8;   // 8 x bf16
typedef __attribute__((ext_vector_type(4))) float floatx4;

__device__ __forceinline__ float gelu_fast(float x) {
    // 0.5x(1+tanh(c(x+0.044715x^3))) == x*sigmoid(2c x (1+0.044715x^2))
    float u = 1.5957691216057308f * x * (1.0f + 0.044715f * x * x);
    return x / (1.0f + __expf(-u));
}

__device__ __forceinline__ unsigned short f2bf(float f) {   // RNE fp32->bf16
    unsigned u = __float_as_uint(f);
    u += 0x7fffu + ((u >> 16) & 1);
    return (unsigned short)(u >> 16);
}

__device__ __forceinline__ float bf2f(unsigned short h) {
    return __uint_as_float((unsigned)h << 16);
}

__device__ __forceinline__ void up8(uint4 u, float* f) {    // 8 bf16 -> 8 fp32
    f[0] = __uint_as_float(u.x << 16); f[1] = __uint_as_float(u.x & 0xffff0000u);
    f[2] = __uint_as_float(u.y << 16); f[3] = __uint_as_float(u.y & 0xffff0000u);
    f[4] = __uint_as_float(u.z << 16); f[5] = __uint_as_float(u.z & 0xffff0000u);
    f[6] = __uint_as_float(u.w << 16); f[7] = __uint_as_float(u.w & 0xffff0000u);
}

__device__ __forceinline__ uint4 pk8(const float* f) {      // 8 fp32 -> 8 bf16
    uint4 u;
    u.x = (unsigned)f2bf(f[0]) | ((unsigned)f2bf(f[1]) << 16);
    u.y = (unsigned)f2bf(f[2]) | ((unsigned)f2bf(f[3]) << 16);
    u.z = (unsigned)f2bf(f[4]) | ((unsigned)f2bf(f[5]) << 16);
    u.w = (unsigned)f2bf(f[6]) | ((unsigned)f2bf(f[7]) << 16);
    return u;
}

// ---------------- fused A-resident streaming MFMA GEMM (packed proj) -------
// Frag layouts (verified m89): A[m=lane&15][k=quad*8+j],
// B[k=quad*8+j][n=lane&15], D[row=quad*4+reg][col=lane&15].
// One launch covers road [0,938) / poi [938,1408) / region [1408,1549).
__global__ __launch_bounds__(256) void gemm_proj_all(
    const unsigned short* __restrict__ xs_bf,
    const unsigned short* __restrict__ Wl,     // Wpack + l*180224
    const float* __restrict__ bl,              // bpack + l*1408
    unsigned short* __restrict__ proj)
{
    const int    NN_[3]  = {30000, 60000, 6000};
    const int    OFFr[3] = {0, 30000, 90000};
    const int    WOFF[3] = {0, 49152, 131072};
    const int    BOFF[3] = {0, 384, 1024};
    const size_t POFF[3] = {0, 11520000u, 49920000u};
    const int    LDO[3]  = {384, 640, 384};
    const int    CPBv[3] = {3, 5, 2};

    int by = blockIdx.x, t, lb;
    if (by < 938)       { t = 1; lb = by; }
    else if (by < 1408) { t = 0; lb = by - 938; }
    else                { t = 2; lb = by - 1408; }
    int bx, byy;
    if (t == 2) { byy = lb / 3; bx = lb - byy * 3; }
    else        { bx = lb & 1; byy = lb >> 1; }

    const unsigned short* Abf = xs_bf + (size_t)OFFr[t] * 128;
    const unsigned short* Wt  = Wl + WOFF[t];
    const float* bias = bl + BOFF[t];
    unsigned short* outbf = proj + POFF[t];
    const int ldo = LDO[t], Nrows = NN_[t], cpb = CPBv[t], nct = ldo >> 6;

    const int wave = threadIdx.x >> 6, lane = threadIdx.x & 63;
    const int quad = lane >> 4, l16 = lane & 15;
    const int rowStart = (byy * 4 + wave) * 32;
    if (rowStart >= Nrows) return;
    short8 Afr[2][4];
    #pragma unroll
    for (int rt = 0; rt < 2; ++rt) {
        int m = rowStart + rt * 16 + l16;
        const unsigned short* ap = Abf + (size_t)((m < Nrows) ? m : 0) * 128 + quad * 8;
        #pragma unroll
        for (int kc = 0; kc < 4; ++kc)
            Afr[rt][kc] = *(const short8*)(ap + kc * 32);
    }
    int ct1 = bx * cpb + cpb;
    if (ct1 > nct) ct1 = nct;
    for (int ct = bx * cpb; ct < ct1; ++ct) {
        int colBase = ct * 64;
        const unsigned short* wp = Wt + (size_t)(colBase + l16) * 128 + quad * 8;
        short8 B[4][4];
        #pragma unroll
        for (int c = 0; c < 4; ++c)
            #pragma unroll
            for (int kc = 0; kc < 4; ++kc)
                B[c][kc] = *(const short8*)(wp + (size_t)c * 2048 + kc * 32);
        floatx4 acc[2][4] = {{{0,0,0,0},{0,0,0,0},{0,0,0,0},{0,0,0,0}},
                             {{0,0,0,0},{0,0,0,0},{0,0,0,0},{0,0,0,0}}};
        #pragma unroll
        for (int kc = 0; kc < 4; ++kc)
            #pragma unroll
            for (int c = 0; c < 4; ++c) {
                acc[0][c] = __builtin_amdgcn_mfma_f32_16x16x32_bf16(Afr[0][kc], B[c][kc], acc[0][c], 0, 0, 0);
                acc[1][c] = __builtin_amdgcn_mfma_f32_16x16x32_bf16(Afr[1][kc], B[c][kc], acc[1][c], 0, 0, 0);
            }
        #pragma unroll
        for (int rt = 0; rt < 2; ++rt) {
            int row0 = rowStart + rt * 16 + quad * 4;
            #pragma unroll
            for (int c = 0; c < 4; ++c) {
                int col = colBase + c * 16 + l16;
                float bv = bias[col];
                #pragma unroll
                for (int r = 0; r < 4; ++r) {
                    int row = row0 + r;
                    if (row < Nrows)
                        outbf[(size_t)row * ldo + col] = f2bf(acc[rt][c][r] + bv);
                }
            }
        }
    }
}

// ---------------- fused-by-type node GEMM (input linear / node update) -----
// 16 rows/wave, 64/block; stripes: poi 469 / road 938 / region 94 (1501 total)
template<bool AF32, bool GIN, bool SKIP>
__global__ __launch_bounds__(256) void gemm_node(
    const void* __restrict__ a0v, const void* __restrict__ a1v, const void* __restrict__ a2v,
    const unsigned short* __restrict__ WtB, const float* __restrict__ biasB,
    const unsigned short* __restrict__ xoldB, const float* __restrict__ skipB,
    unsigned short* __restrict__ outB)
{
    const int TN[3]   = {30000, 60000, 6000};
    const int TOFF[3] = {0, 30000, 90000};
    int by = blockIdx.x;
    int t  = (by < 469) ? 0 : (by < 1407) ? 1 : 2;
    int lb = by - ((t == 0) ? 0 : (t == 1) ? 469 : 1407);
    int Nrows = TN[t];
    const void* av = (t == 0) ? a0v : (t == 1) ? a1v : a2v;
    const unsigned short* Wt = WtB + (size_t)t * 16384;
    const float* bias = biasB + t * 128;
    const unsigned short* xold = xoldB + (size_t)TOFF[t] * 128;
    unsigned short* out = outB + (size_t)TOFF[t] * 128;
    const int wave = threadIdx.x >> 6, lane = threadIdx.x & 63;
    const int quad = lane >> 4, l16 = lane & 15;
    const int rowStart = (lb * 4 + wave) * 16;
    if (rowStart >= Nrows) return;
    int m = rowStart + l16;
    size_t base = (size_t)((m < Nrows) ? m : 0) * 128 + quad * 8;
    short8 Afr[4];
    #pragma unroll
    for (int kc = 0; kc < 4; ++kc) {
        if (AF32) {
            const float* ap = (const float*)av + base;
            float4 f0 = *(const float4*)(ap + kc * 32);
            float4 f1 = *(const float4*)(ap + kc * 32 + 4);
            float af[8] = {f0.x, f0.y, f0.z, f0.w, f1.x, f1.y, f1.z, f1.w};
            short8 a;
            #pragma unroll
            for (int i = 0; i < 8; ++i) a[i] = (short)f2bf(af[i]);
            Afr[kc] = a;
        } else if (GIN) {
            const unsigned short* ap = (const unsigned short*)av + base;
            short8 a8 = *(const short8*)(ap + kc * 32);
            short8 a;
            #pragma unroll
            for (int i = 0; i < 8; ++i)
                a[i] = (short)f2bf(gelu_fast(bf2f((unsigned short)a8[i])));
            Afr[kc] = a;
        } else {
            const unsigned short* ap = (const unsigned short*)av + base;
            Afr[kc] = *(const short8*)(ap + kc * 32);
        }
    }
    float beta = 0.f, omb = 0.f;
    if (SKIP) { beta = 1.0f / (1.0f + __expf(-skipB[t])); omb = 1.0f - beta; }
    int row0 = rowStart + quad * 4;
    #pragma unroll
    for (int ct = 0; ct < 2; ++ct) {
        int colBase = ct * 64;
        const unsigned short* wp = Wt + (size_t)(colBase + l16) * 128 + quad * 8;
        #pragma unroll
        for (int c = 0; c < 4; ++c) {
            floatx4 acc = {0, 0, 0, 0};
            #pragma unroll
            for (int kc = 0; kc < 4; ++kc) {
                short8 B = *(const short8*)(wp + (size_t)c * 2048 + kc * 32);
                acc = __builtin_amdgcn_mfma_f32_16x16x32_bf16(Afr[kc], B, acc, 0, 0, 0);
            }
            int col = colBase + c * 16 + l16;
            float bv = bias[col];
            #pragma unroll
            for (int r = 0; r < 4; ++r) {
                int row = row0 + r;
                if (row < Nrows) {
                    float o = acc[r] + bv;
                    if (SKIP) o = beta * o + omb * bf2f(xold[(size_t)row * 128 + col]);
                    o = fmaxf(o, 0.f);
                    out[(size_t)row * 128 + col] = f2bf(o);
                }
            }
        }
    }
}

// ---------------- output projection: one GEMM over all 96000 rows ----------
__global__ __launch_bounds__(256) void gemm_out(
    const unsigned short* __restrict__ Abf,
    const unsigned short* __restrict__ Wt,     // [64][128] bf16^T
    const float* __restrict__ bias,
    float* __restrict__ out, int Nrows)
{
    const int wave = threadIdx.x >> 6, lane = threadIdx.x & 63;
    const int quad = lane >> 4, l16 = lane & 15;
    const int rowBase = (blockIdx.x * 4 + wave) * 16;
    if (rowBase >= Nrows) return;
    const unsigned short* wp = Wt + (size_t)l16 * 128 + quad * 8;
    int m = rowBase + l16;
    const unsigned short* ap = Abf + (size_t)((m < Nrows) ? m : 0) * 128 + quad * 8;
    short8 Afr[4];
    #pragma unroll
    for (int kc = 0; kc < 4; ++kc) Afr[kc] = *(const short8*)(ap + kc * 32);
    int row0 = rowBase + quad * 4;
    #pragma unroll
    for (int c = 0; c < 4; ++c) {
        floatx4 acc = {0, 0, 0, 0};
        #pragma unroll
        for (int kc = 0; kc < 4; ++kc) {
            short8 B = *(const short8*)(wp + (size_t)c * 2048 + kc * 32);
            acc = __builtin_amdgcn_mfma_f32_16x16x32_bf16(Afr[kc], B, acc, 0, 0, 0);
        }
        int col = c * 16 + l16;
        float bv = bias[col];
        #pragma unroll
        for (int r = 0; r < 4; ++r) {
            int row = row0 + r;
            if (row < Nrows)
                out[(size_t)row * 64 + col] = acc[r] + bv;
        }
    }
}

// ------------------------- weight prep -------------------------------------
__global__ __launch_bounds__(128) void prep_qpack(
    const float* __restrict__ qw, const float* __restrict__ qb,
    unsigned short* __restrict__ Wpack, float* __restrict__ bpack)
{
    const int pre[3] = {0, 49152, 131072};
    const int preB[3] = {0, 384, 1024};
    int n = threadIdx.x, k = blockIdx.x, t = blockIdx.y, l = blockIdx.z;
    unsigned short* Wp = Wpack + (size_t)l * 180224 + pre[t];
    Wp[(size_t)n * 128 + k] = f2bf(qw[(size_t)(l * 3 + t) * 16384 + (size_t)k * 128 + n]);
    if (k == 0) bpack[l * 1408 + preB[t] + n] = qb[(l * 3 + t) * 128 + n];
}

__global__ __launch_bounds__(128) void fold_rel_pack(
    const float* __restrict__ kw, const float* __restrict__ kb,
    const float* __restrict__ vw, const float* __restrict__ vb,
    const float* __restrict__ a_rel, const float* __restrict__ m_rel,
    unsigned short* __restrict__ Wpack, float* __restrict__ bpack)
{
    const int SIv[4] = {0, 1, 1, 2};
    const int SLOT[4] = {0, 0, 1, 0};
    const int pre[3] = {0, 49152, 131072};
    const int preB[3] = {0, 384, 1024};
    int hf = threadIdx.x, h = hf >> 4, f = hf & 15;
    int c = blockIdx.x, et = blockIdx.y, l = blockIdx.z;
    int si = SIv[et];
    const float* kwp  = kw + (size_t)(l * 3 + si) * 16384;
    const float* vwp  = vw + (size_t)(l * 3 + si) * 16384;
    const float* kbp  = kb + (size_t)(l * 3 + si) * 128;
    const float* vbp  = vb + (size_t)(l * 3 + si) * 128;
    const float* arel = a_rel + (size_t)(l * 4 + et) * 2048;
    const float* mrel = m_rel + (size_t)(l * 4 + et) * 2048;
    float sk = 0.f, sv = 0.f;
    #pragma unroll
    for (int d = 0; d < 16; ++d) {
        float ar = arel[(h * 16 + d) * 16 + f];
        float mr = mrel[(h * 16 + d) * 16 + f];
        sk = fmaf(kwp[c * 128 + h * 16 + d], ar, sk);
        sv = fmaf(vwp[c * 128 + h * 16 + d], mr, sv);
    }
    int rowoff = 128 + 256 * SLOT[et];
    unsigned short* Wp = Wpack + (size_t)l * 180224 + pre[si];
    Wp[(size_t)(rowoff + hf) * 128 + c]       = f2bf(sk);
    Wp[(size_t)(rowoff + 128 + hf) * 128 + c] = f2bf(sv);
    if (c == 0) {
        float bk = 0.f, bvv = 0.f;
        #pragma unroll
        for (int d = 0; d < 16; ++d) {
            bk  = fmaf(kbp[h * 16 + d], arel[(h * 16 + d) * 16 + f], bk);
            bvv = fmaf(vbp[h * 16 + d], mrel[(h * 16 + d) * 16 + f], bvv);
        }
        float* bp = bpack + l * 1408 + preB[si];
        bp[rowoff + hf]       = bk;
        bp[rowoff + 128 + hf] = bvv;
    }
}

__global__ __launch_bounds__(128) void prep_w9(
    const float* __restrict__ lin_w, const float* __restrict__ aw,
    unsigned short* __restrict__ lwt, unsigned short* __restrict__ awt)
{
    int n = threadIdx.x, k = blockIdx.x, mi = blockIdx.y;
    const float* w; unsigned short* wt; int m;
    if (mi < 3) { w = lin_w; wt = lwt; m = mi; }
    else        { w = aw;    wt = awt; m = mi - 3; }
    wt[(size_t)m * 16384 + (size_t)n * 128 + k] =
        f2bf(w[(size_t)m * 16384 + (size_t)k * 128 + n]);
}

__global__ __launch_bounds__(64) void prep_owt(
    const float* __restrict__ ow, unsigned short* __restrict__ owt)
{
    int n = threadIdx.x, k = blockIdx.x;
    owt[(size_t)n * 128 + k] = f2bf(ow[(size_t)k * 64 + n]);
}

// ------------------------- CSR build (fused across edge types) --------------
__global__ __launch_bounds__(256) void hist_all(
    const int* __restrict__ d0, const int* __restrict__ d1,
    const int* __restrict__ d2, const int* __restrict__ d3,
    int* __restrict__ deg4)
{
    const int Ev[4] = {200000, 300000, 200000, 100000};
    int et = blockIdx.y;
    int e = blockIdx.x * 256 + threadIdx.x;
    if (e >= Ev[et]) return;
    const int* d = et == 0 ? d0 : et == 1 ? d1 : et == 2 ? d2 : d3;
    atomicAdd(&deg4[et * 60000 + d[e]], 1);
}

__global__ __launch_bounds__(256) void scan_tile_all(
    const int* __restrict__ deg4,
    int* __restrict__ r0, int* __restrict__ r1, int* __restrict__ r2, int* __restrict__ r3,
    int* __restrict__ tsum4)
{
    const int Ndv[4] = {60000, 60000, 6000, 30000};
    __shared__ int ls[256];
    int et = blockIdx.y;
    int n = Ndv[et];
    const int* deg = deg4 + et * 60000;
    int* rowptr = et == 0 ? r0 : et == 1 ? r1 : et == 2 ? r2 : r3;
    int b = blockIdx.x, tid = threadIdx.x;
    int base = b * 1024 + tid * 4;
    int v0 = 0, v1 = 0, v2 = 0, v3 = 0;
    if (base + 3 < n) {
        int4 t = *(const int4*)(deg + base);
        v0 = t.x; v1 = t.y; v2 = t.z; v3 = t.w;
    } else {
        if (base + 0 < n) v0 = deg[base + 0];
        if (base + 1 < n) v1 = deg[base + 1];
        if (base + 2 < n) v2 = deg[base + 2];
        if (base + 3 < n) v3 = deg[base + 3];
    }
    int s = v0 + v1 + v2 + v3;
    ls[tid] = s;
    __syncthreads();
    #pragma unroll
    for (int off = 1; off < 256; off <<= 1) {
        int t = (tid >= off) ? ls[tid - off] : 0;
        __syncthreads();
        ls[tid] += t;
        __syncthreads();
    }
    int run = ls[tid] - s;
    int o0 = run; run += v0;
    int o1 = run; run += v1;
    int o2 = run; run += v2;
    int o3 = run;
    if (base + 3 < n) {
        *(int4*)(rowptr + base) = make_int4(o0, o1, o2, o3);
    } else {
        if (base + 0 < n) rowptr[base + 0] = o0;
        if (base + 1 < n) rowptr[base + 1] = o1;
        if (base + 2 < n) rowptr[base + 2] = o2;
    }
    if (tid == 255) tsum4[et * 64 + b] = ls[255];
}

__global__ __launch_bounds__(64) void scan_tsum_all(
    int* __restrict__ tsum4,
    int* __restrict__ r0, int* __restrict__ r1, int* __restrict__ r2, int* __restrict__ r3)
{
    const int Ndv[4] = {60000, 60000, 6000, 30000};
    int et = blockIdx.x;
    int n = Ndv[et];
    int nt = (n + 1023) >> 10;
    int* tileSum = tsum4 + et * 64;
    int* rowptr = et == 0 ? r0 : et == 1 ? r1 : et == 2 ? r2 : r3;
    int tid = threadIdx.x;
    int v = (tid < nt) ? tileSum[tid] : 0;
    int orig = v;
    #pragma unroll
    for (int off = 1; off < 64; off <<= 1) {
        int t = __shfl_up(v, off);
        if (tid >= off) v += t;
    }
    if (tid < nt) tileSum[tid] = v - orig;
    if (tid == nt - 1) rowptr[n] = v;
}

__global__ __launch_bounds__(256) void scan_add_all(
    int* __restrict__ r0, int* __restrict__ r1, int* __restrict__ r2, int* __restrict__ r3,
    const int* __restrict__ tsum4)
{
    const int Ndv[4] = {60000, 60000, 6000, 30000};
    int et = blockIdx.y;
    int n = Ndv[et];
    int* rowptr = et == 0 ? r0 : et == 1 ? r1 : et == 2 ? r2 : r3;
    int i = blockIdx.x * 256 + threadIdx.x;
    if (i < n) rowptr[i] += tsum4[et * 64 + (i >> 10)];
}

__global__ __launch_bounds__(256) void fill_all(
    const int* __restrict__ s0, const int* __restrict__ d0,
    const int* __restrict__ s1, const int* __restrict__ d1,
    const int* __restrict__ s2, const int* __restrict__ d2,
    const int* __restrict__ s3, const int* __restrict__ d3,
    const int* __restrict__ r0, const int* __restrict__ r1,
    const int* __restrict__ r2, const int* __restrict__ r3,
    int* __restrict__ deg4,
    int* __restrict__ c0, int* __restrict__ c1, int* __restrict__ c2, int* __restrict__ c3)
{
    const int Ev[4] = {200000, 300000, 200000, 100000};
    int et = blockIdx.y;
    int e = blockIdx.x * 256 + threadIdx.x;
    if (e >= Ev[et]) return;
    const int* src = et == 0 ? s0 : et == 1 ? s1 : et == 2 ? s2 : s3;
    const int* dst = et == 0 ? d0 : et == 1 ? d1 : et == 2 ? d2 : d3;
    const int* rowptr = et == 0 ? r0 : et == 1 ? r1 : et == 2 ? r2 : r3;
    int* csr = et == 0 ? c0 : et == 1 ? c1 : et == 2 ? c2 : c3;
    int d = dst[e];
    int pos = atomicAdd(&deg4[et * 60000 + d], 1);
    csr[rowptr[d] + pos] = src[e];
}

// --------------- merged gather-side attention (all 4 edge types) ------------
// Software-pipelined: edge j+1's K/V loads issue before edge j's compute.
// Defer-max (THR=8): o-rescale only when the running max grows by >8;
// exact math (o and l always carry the common factor exp(-m)).
__device__ __forceinline__ void attn_run(
    const int* __restrict__ csr, int beg, int end,
    const unsigned short* __restrict__ kbase, int ld,
    const float* qf, float ph, float& m, float& l, float* o)
{
    if (beg >= end) return;
    int s = csr[beg];
    const uint4* kp = (const uint4*)(kbase + (size_t)s * ld);
    uint4 ku0 = kp[0], ku1 = kp[1];
    uint4 vu0 = kp[16], vu1 = kp[17];       // mv at +128 shorts
    for (int j = beg; j < end; ++j) {
        uint4 nk0 = ku0, nk1 = ku1, nv0 = vu0, nv1 = vu1;
        if (j + 1 < end) {                  // prefetch next edge
            int sn = csr[j + 1];
            const uint4* np = (const uint4*)(kbase + (size_t)sn * ld);
            nk0 = np[0]; nk1 = np[1]; nv0 = np[16]; nv1 = np[17];
        }
        float kf[16], vf[16];
        up8(ku0, kf); up8(ku1, kf + 8);
        up8(vu0, vf); up8(vu1, vf + 8);
        float a = 0.f;
        #pragma unroll
        for (int i = 0; i < 16; ++i) a = fmaf(qf[i], kf[i], a);
        a *= ph;
        float d = a - m;
        if (d > 8.f) {                      // rare after first edge
            float sc = __expf(-d);
            l *= sc;
            #pragma unroll
            for (int i = 0; i < 16; ++i) o[i] *= sc;
            m = a; d = 0.f;
        }
        float w = __expf(d);                // d <= 8 -> w <= e^8
        l += w;
        #pragma unroll
        for (int i = 0; i < 16; ++i) o[i] = fmaf(w, vf[i], o[i]);
        ku0 = nk0; ku1 = nk1; vu0 = nv0; vu1 = nv1;
    }
}

// grid: [0,1875) road(et0+et1 serial) / [1875,2625) region(et2, 4-way split) /
//       [2625,3563) poi(et3)
__global__ __launch_bounds__(256) void agg_all(
    const int* __restrict__ rp0, const int* __restrict__ cs0,
    const int* __restrict__ rp1, const int* __restrict__ cs1,
    const int* __restrict__ rp2, const int* __restrict__ cs2,
    const int* __restrict__ rp3, const int* __restrict__ cs3,
    const unsigned short* __restrict__ P0, const unsigned short* __restrict__ P1,
    const unsigned short* __restrict__ P2,
    const float* __restrict__ prl,      // p_rel + l*32
    unsigned short* __restrict__ num)
{
    int gb = blockIdx.x, tid = threadIdx.x;
    float qf[16], o[16], r[16];
    if (gb < 1875) {
        // ---- road: et0 (poi src) + et1 (road src), separate softmaxes ----
        int t = gb * 256 + tid;            // < 480000 exactly
        int node = t >> 3, h = t & 7;
        const uint4* qp = (const uint4*)(P1 + (size_t)node * 640 + h * 16);
        up8(qp[0], qf); up8(qp[1], qf + 8);
        float m0 = -INFINITY, l0 = 0.f;
        #pragma unroll
        for (int i = 0; i < 16; ++i) o[i] = 0.f;
        attn_run(cs0, rp0[node], rp0[node + 1], P0 + 128 + h * 16, 384,
                 qf, prl[h] * 0.25f, m0, l0, o);
        float i0 = 1.f / (l0 + 1e-16f);
        #pragma unroll
        for (int i = 0; i < 16; ++i) { r[i] = i0 * o[i]; o[i] = 0.f; }
        float m1 = -INFINITY, l1 = 0.f;
        attn_run(cs1, rp1[node], rp1[node + 1], P1 + 128 + h * 16, 640,
                 qf, prl[8 + h] * 0.25f, m1, l1, o);
        float i1 = 1.f / (l1 + 1e-16f);
        #pragma unroll
        for (int i = 0; i < 16; ++i) r[i] += i1 * o[i];
        uint4* np = (uint4*)(num + (size_t)(30000 + node) * 128 + h * 16);
        np[0] = pk8(r); np[1] = pk8(r + 8);
    } else if (gb < 2625) {
        // ---- region: et2 (road src), 4-way edge split + shuffle merge ----
        int t = (gb - 1875) * 256 + tid;   // < 192000 exactly
        int node = t >> 5, h = t & 7, sub = (t >> 3) & 3;
        int beg0 = rp2[node], end0 = rp2[node + 1];
        int n = end0 - beg0;
        int beg = beg0 + ((n * sub) >> 2);
        int end = beg0 + ((n * (sub + 1)) >> 2);
        const uint4* qp = (const uint4*)(P2 + (size_t)node * 384 + h * 16);
        up8(qp[0], qf); up8(qp[1], qf + 8);
        float m = -INFINITY, l = 0.f;
        #pragma unroll
        for (int i = 0; i < 16; ++i) o[i] = 0.f;
        attn_run(cs2, beg, end, P1 + 384 + h * 16, 640,
                 qf, prl[16 + h] * 0.25f, m, l, o);
        #pragma unroll
        for (int st = 8; st <= 16; st <<= 1) {
            float mp = __shfl_xor(m, st);
            float lp = __shfl_xor(l, st);
            float mn = fmaxf(m, mp);
            float sc  = (l  > 0.f) ? __expf(m  - mn) : 0.f;
            float scp = (lp > 0.f) ? __expf(mp - mn) : 0.f;
            l = l * sc + lp * scp;
            #pragma unroll
            for (int i = 0; i < 16; ++i) {
                float op = __shfl_xor(o[i], st);
                o[i] = o[i] * sc + op * scp;
            }
            m = mn;
        }
        if (sub) return;
        float inv = 1.f / (l + 1e-16f);
        #pragma unroll
        for (int i = 0; i < 16; ++i) r[i] = inv * o[i];
        uint4* np = (uint4*)(num + (size_t)(90000 + node) * 128 + h * 16);
        np[0] = pk8(r); np[1] = pk8(r + 8);
    } else {
        // ---- poi: et3 (region src) ----
        int t = (gb - 2625) * 256 + tid;
        if (t >= 240000) return;
        int node = t >> 3, h = t & 7;
        const uint4* qp = (const uint4*)(P0 + (size_t)node * 384 + h * 16);
        up8(qp[0], qf); up8(qp[1], qf + 8);
        float m = -INFINITY, l = 0.f;
        #pragma unroll
        for (int i = 0; i < 16; ++i) o[i] = 0.f;
        attn_run(cs3, rp3[node], rp3[node + 1], P2 + 128 + h * 16, 384,
                 qf, prl[24 + h] * 0.25f, m, l, o);
        float inv = 1.f / (l + 1e-16f);
        #pragma unroll
        for (int i = 0; i < 16; ++i) r[i] = inv * o[i];
        uint4* np = (uint4*)(num + (size_t)node * 128 + h * 16);
        np[0] = pk8(r); np[1] = pk8(r + 8);
    }
}

extern "C" void kernel_launch(void* const* d_in, const int* in_sizes, int n_in,
                              void* d_out, int out_size, void* d_ws, size_t ws_size,
                              hipStream_t stream)
{
    (void)in_sizes; (void)n_in; (void)out_size; (void)ws_size;

    const float* xin[3] = {(const float*)d_in[0], (const float*)d_in[1], (const float*)d_in[2]};
    const int* esrc[4] = {(const int*)d_in[3], (const int*)d_in[5], (const int*)d_in[7], (const int*)d_in[9]};
    const int* edst[4] = {(const int*)d_in[4], (const int*)d_in[6], (const int*)d_in[8], (const int*)d_in[10]};
    const float* lin_w = (const float*)d_in[11];
    const float* lin_b = (const float*)d_in[12];
    const float* kw = (const float*)d_in[13];
    const float* qw = (const float*)d_in[14];
    const float* vw = (const float*)d_in[15];
    const float* aw = (const float*)d_in[16];
    const float* kb = (const float*)d_in[17];
    const float* qb = (const float*)d_in[18];
    const float* vb = (const float*)d_in[19];
    const float* ab = (const float*)d_in[20];
    const float* a_rel = (const float*)d_in[21];
    const float* m_rel = (const float*)d_in[22];
    const float* p_rel = (const float*)d_in[23];
    const float* skip  = (const float*)d_in[24];
    const float* out_w = (const float*)d_in[25];
    const float* out_b = (const float*)d_in[26];

    // workspace (float-index units; ~39.9M floats = 160 MB)
    float* ws = (float*)d_ws;
    unsigned short* num   = (unsigned short*)ws;                // 12,288,000 h
    unsigned short* xs_bf = (unsigned short*)(ws + 6144000);    // 12,288,000 h
    unsigned short* proj  = (unsigned short*)(ws + 12288000);   // 52,224,000 h
    unsigned short* Wpack = (unsigned short*)(ws + 38400000);   // 360,448 h
    unsigned short* lwt   = (unsigned short*)(ws + 38580224);   // 49,152 h
    unsigned short* awt   = (unsigned short*)(ws + 38604800);   // 98,304 h
    unsigned short* owt   = (unsigned short*)(ws + 38653952);   // 8,192 h
    float*          bpack = ws + 38658048;                      // 2,816 f
    int*            deg4  = (int*)(ws + 38660864);              // 240,000
    int*            tsum4 = (int*)(ws + 38900864);              // 256
    int* rp[4];
    rp[0] = (int*)(ws + 38901120);                              // 60,008
    rp[1] = (int*)(ws + 38961128);
    rp[2] = (int*)(ws + 39021136);                              // 6,008
    rp[3] = (int*)(ws + 39027144);                              // 30,008
    int* cs[4];
    cs[0] = (int*)(ws + 39057152);                              // 200,000
    cs[1] = (int*)(ws + 39257152);                              // 300,000
    cs[2] = (int*)(ws + 39557152);                              // 200,000
    cs[3] = (int*)(ws + 39757152);                              // 100,000

    unsigned short* P[3];
    P[0] = proj;
    P[1] = proj + (size_t)30000 * 384;
    P[2] = proj + (size_t)30000 * 384 + (size_t)60000 * 640;

    dim3 blk(256);

    // ---- CSR build, fused across edge types ----
    hipMemsetAsync(deg4, 0, 960000, stream);
    hist_all<<<dim3(1172, 4), blk, 0, stream>>>(edst[0], edst[1], edst[2], edst[3], deg4);
    scan_tile_all<<<dim3(59, 4), blk, 0, stream>>>(deg4, rp[0], rp[1], rp[2], rp[3], tsum4);
    scan_tsum_all<<<dim3(4), dim3(64), 0, stream>>>(tsum4, rp[0], rp[1], rp[2], rp[3]);
    scan_add_all<<<dim3(235, 4), blk, 0, stream>>>(rp[0], rp[1], rp[2], rp[3], tsum4);
    hipMemsetAsync(deg4, 0, 960000, stream);
    fill_all<<<dim3(1172, 4), blk, 0, stream>>>(
        esrc[0], edst[0], esrc[1], edst[1], esrc[2], edst[2], esrc[3], edst[3],
        rp[0], rp[1], rp[2], rp[3], deg4, cs[0], cs[1], cs[2], cs[3]);

    // ---- weight prep ----
    prep_qpack<<<dim3(128, 3, 2), dim3(128), 0, stream>>>(qw, qb, Wpack, bpack);
    fold_rel_pack<<<dim3(128, 4, 2), dim3(128), 0, stream>>>(
        kw, kb, vw, vb, a_rel, m_rel, Wpack, bpack);
    prep_w9<<<dim3(128, 9), dim3(128), 0, stream>>>(lin_w, aw, lwt, awt);
    prep_owt<<<dim3(128), dim3(64), 0, stream>>>(out_w, owt);

    // ---- input linear + relu -> xs_bf (fused across types) ----
    gemm_node<true, false, false><<<dim3(1501), blk, 0, stream>>>(
        xin[0], xin[1], xin[2], lwt, lin_b, nullptr, nullptr, xs_bf);

    for (int l = 0; l < 2; ++l) {
        // packed projection per node type: [q | ka|mv ...], one fused launch
        gemm_proj_all<<<dim3(1549), blk, 0, stream>>>(
            xs_bf, Wpack + (size_t)l * 180224, bpack + l * 1408, proj);

        // merged aggregation: all 4 edge types in one launch
        agg_all<<<dim3(3563), blk, 0, stream>>>(
            rp[0], cs[0], rp[1], cs[1], rp[2], cs[2], rp[3], cs[3],
            P[0], P[1], P[2], p_rel + (size_t)l * 32, num);

        // node update (fused across types)
        gemm_node<false, true, true><<<dim3(1501), blk, 0, stream>>>(
            num, num + (size_t)30000 * 128, num + (size_t)90000 * 128,
            awt + (size_t)l * 3 * 16384, ab + (size_t)l * 3 * 128,
            xs_bf, skip + l * 3, xs_bf);
    }

    // ---- output projection: single GEMM over all 96000 rows ----
    gemm_out<<<dim3(1500), blk, 0, stream>>>(
        xs_bf, owt, out_b, (float*)d_out, 96000);
}

// Round 2
// 640.905 us; speedup vs baseline: 1.0450x; 1.0243x over previous
//
#include <hip/hip_runtime.h>
#include <cstddef>
#include <cstdint>

// ---------------------------------------------------------------------------
// HGT forward for MI355X. C=128, H=8, D=16, OUT=64, L=2
//   NN = {30000, 60000, 6000}, NE = {200000, 300000, 200000, 100000}
//   ETS = {(0,1),(1,1),(1,2),(2,0)}
// Round-11 changes:
//  * All MFMA GEMMs: operand swap mfma(W,X) -> D[outcol][node]; each lane
//    holds 4 consecutive output cols of one node -> 8B uint2 stores (proj,
//    node) / 16B float4 stores (out). Was 2B scalar stores, 32 instrs/tile.
//    gemm_proj_all was issue/latency-bound: 17% HBM, 8% VALU, 5% MFMA.
//  * gemm_proj_all: uniform 2 column-tiles per block (road 469x5, poi 235x3,
//    region 47x3 = 3191 blocks) -- removes road-tail imbalance (occ 32%).
// ---------------------------------------------------------------------------

typedef __attribute__((ext_vector_type(8))) short short8;   // 8 x bf16
typedef __attribute__((ext_vector_type(4))) float floatx4;

__device__ __forceinline__ float gelu_fast(float x) {
    // 0.5x(1+tanh(c(x+0.044715x^3))) == x*sigmoid(2c x (1+0.044715x^2))
    float u = 1.5957691216057308f * x * (1.0f + 0.044715f * x * x);
    return x / (1.0f + __expf(-u));
}

__device__ __forceinline__ unsigned short f2bf(float f) {   // RNE fp32->bf16
    unsigned u = __float_as_uint(f);
    u += 0x7fffu + ((u >> 16) & 1);
    return (unsigned short)(u >> 16);
}

__device__ __forceinline__ float bf2f(unsigned short h) {
    return __uint_as_float((unsigned)h << 16);
}

__device__ __forceinline__ void up8(uint4 u, float* f) {    // 8 bf16 -> 8 fp32
    f[0] = __uint_as_float(u.x << 16); f[1] = __uint_as_float(u.x & 0xffff0000u);
    f[2] = __uint_as_float(u.y << 16); f[3] = __uint_as_float(u.y & 0xffff0000u);
    f[4] = __uint_as_float(u.z << 16); f[5] = __uint_as_float(u.z & 0xffff0000u);
    f[6] = __uint_as_float(u.w << 16); f[7] = __uint_as_float(u.w & 0xffff0000u);
}

__device__ __forceinline__ uint4 pk8(const float* f) {      // 8 fp32 -> 8 bf16
    uint4 u;
    u.x = (unsigned)f2bf(f[0]) | ((unsigned)f2bf(f[1]) << 16);
    u.y = (unsigned)f2bf(f[2]) | ((unsigned)f2bf(f[3]) << 16);
    u.z = (unsigned)f2bf(f[4]) | ((unsigned)f2bf(f[5]) << 16);
    u.w = (unsigned)f2bf(f[6]) | ((unsigned)f2bf(f[7]) << 16);
    return u;
}

// ---------------- fused A-resident streaming MFMA GEMM (packed proj) -------
// Frag layouts (verified m89): A[m=lane&15][k=quad*8+j],
// B[k=quad*8+j][n=lane&15], D[row=quad*4+reg][col=lane&15].
// Operand-swapped: mfma(Wfrag, Xfrag) -> D[outcol=quad*4+reg][node=l16];
// lane stores 4 consecutive bf16 cols of one node as one uint2 (8B).
// Blocks: road [0,2345)=469x5 / poi [2345,3050)=235x3 / region [3050,3191)
// = 47x3; every block does exactly 2 column-tiles (uniform work).
__global__ __launch_bounds__(256) void gemm_proj_all(
    const unsigned short* __restrict__ xs_bf,
    const unsigned short* __restrict__ Wl,     // Wpack + l*180224
    const float* __restrict__ bl,              // bpack + l*1408
    unsigned short* __restrict__ proj)
{
    const int    NN_[3]  = {30000, 60000, 6000};
    const int    OFFr[3] = {0, 30000, 90000};
    const int    WOFF[3] = {0, 49152, 131072};
    const int    BOFF[3] = {0, 384, 1024};
    const size_t POFF[3] = {0, 11520000u, 49920000u};
    const int    LDO[3]  = {384, 640, 384};

    int by = blockIdx.x, t, lb;
    if (by < 2345)      { t = 1; lb = by; }
    else if (by < 3050) { t = 0; lb = by - 2345; }
    else                { t = 2; lb = by - 3050; }
    int XG = (t == 1) ? 5 : 3;
    int byy = lb / XG, bx = lb - byy * XG;

    const unsigned short* Abf = xs_bf + (size_t)OFFr[t] * 128;
    const unsigned short* Wt  = Wl + WOFF[t];
    const float* bias = bl + BOFF[t];
    unsigned short* outbf = proj + POFF[t];
    const int ldo = LDO[t], Nrows = NN_[t];

    const int wave = threadIdx.x >> 6, lane = threadIdx.x & 63;
    const int quad = lane >> 4, l16 = lane & 15;
    const int rowStart = (byy * 4 + wave) * 32;
    if (rowStart >= Nrows) return;
    short8 Afr[2][4];
    #pragma unroll
    for (int rt = 0; rt < 2; ++rt) {
        int m = rowStart + rt * 16 + l16;
        const unsigned short* ap = Abf + (size_t)((m < Nrows) ? m : 0) * 128 + quad * 8;
        #pragma unroll
        for (int kc = 0; kc < 4; ++kc)
            Afr[rt][kc] = *(const short8*)(ap + kc * 32);
    }
    int ct0 = bx * 2, ct1 = ct0 + 2;
    for (int ct = ct0; ct < ct1; ++ct) {
        int colBase = ct * 64;
        const unsigned short* wp = Wt + (size_t)(colBase + l16) * 128 + quad * 8;
        short8 B[4][4];
        #pragma unroll
        for (int c = 0; c < 4; ++c)
            #pragma unroll
            for (int kc = 0; kc < 4; ++kc)
                B[c][kc] = *(const short8*)(wp + (size_t)c * 2048 + kc * 32);
        floatx4 acc[2][4] = {{{0,0,0,0},{0,0,0,0},{0,0,0,0},{0,0,0,0}},
                             {{0,0,0,0},{0,0,0,0},{0,0,0,0},{0,0,0,0}}};
        #pragma unroll
        for (int kc = 0; kc < 4; ++kc)
            #pragma unroll
            for (int c = 0; c < 4; ++c) {
                acc[0][c] = __builtin_amdgcn_mfma_f32_16x16x32_bf16(B[c][kc], Afr[0][kc], acc[0][c], 0, 0, 0);
                acc[1][c] = __builtin_amdgcn_mfma_f32_16x16x32_bf16(B[c][kc], Afr[1][kc], acc[1][c], 0, 0, 0);
            }
        #pragma unroll
        for (int rt = 0; rt < 2; ++rt) {
            int node = rowStart + rt * 16 + l16;
            if (node >= Nrows) continue;
            #pragma unroll
            for (int c = 0; c < 4; ++c) {
                int col0 = colBase + c * 16 + quad * 4;
                float4 bv = *(const float4*)(bias + col0);
                uint2 u;
                u.x = (unsigned)f2bf(acc[rt][c][0] + bv.x) |
                      ((unsigned)f2bf(acc[rt][c][1] + bv.y) << 16);
                u.y = (unsigned)f2bf(acc[rt][c][2] + bv.z) |
                      ((unsigned)f2bf(acc[rt][c][3] + bv.w) << 16);
                *(uint2*)(outbf + (size_t)node * ldo + col0) = u;
            }
        }
    }
}

// ---------------- fused-by-type node GEMM (input linear / node update) -----
// 16 rows/wave, 64/block; stripes: poi 469 / road 938 / region 94 (1501 total)
// Operand-swapped epilogue: 8B uint2 stores, 8B skip-read.
template<bool AF32, bool GIN, bool SKIP>
__global__ __launch_bounds__(256) void gemm_node(
    const void* __restrict__ a0v, const void* __restrict__ a1v, const void* __restrict__ a2v,
    const unsigned short* __restrict__ WtB, const float* __restrict__ biasB,
    const unsigned short* __restrict__ xoldB, const float* __restrict__ skipB,
    unsigned short* __restrict__ outB)
{
    const int TN[3]   = {30000, 60000, 6000};
    const int TOFF[3] = {0, 30000, 90000};
    int by = blockIdx.x;
    int t  = (by < 469) ? 0 : (by < 1407) ? 1 : 2;
    int lb = by - ((t == 0) ? 0 : (t == 1) ? 469 : 1407);
    int Nrows = TN[t];
    const void* av = (t == 0) ? a0v : (t == 1) ? a1v : a2v;
    const unsigned short* Wt = WtB + (size_t)t * 16384;
    const float* bias = biasB + t * 128;
    const unsigned short* xold = xoldB + (size_t)TOFF[t] * 128;
    unsigned short* out = outB + (size_t)TOFF[t] * 128;
    const int wave = threadIdx.x >> 6, lane = threadIdx.x & 63;
    const int quad = lane >> 4, l16 = lane & 15;
    const int rowStart = (lb * 4 + wave) * 16;
    if (rowStart >= Nrows) return;
    int m = rowStart + l16;
    size_t base = (size_t)((m < Nrows) ? m : 0) * 128 + quad * 8;
    short8 Afr[4];
    #pragma unroll
    for (int kc = 0; kc < 4; ++kc) {
        if (AF32) {
            const float* ap = (const float*)av + base;
            float4 f0 = *(const float4*)(ap + kc * 32);
            float4 f1 = *(const float4*)(ap + kc * 32 + 4);
            float af[8] = {f0.x, f0.y, f0.z, f0.w, f1.x, f1.y, f1.z, f1.w};
            short8 a;
            #pragma unroll
            for (int i = 0; i < 8; ++i) a[i] = (short)f2bf(af[i]);
            Afr[kc] = a;
        } else if (GIN) {
            const unsigned short* ap = (const unsigned short*)av + base;
            short8 a8 = *(const short8*)(ap + kc * 32);
            short8 a;
            #pragma unroll
            for (int i = 0; i < 8; ++i)
                a[i] = (short)f2bf(gelu_fast(bf2f((unsigned short)a8[i])));
            Afr[kc] = a;
        } else {
            const unsigned short* ap = (const unsigned short*)av + base;
            Afr[kc] = *(const short8*)(ap + kc * 32);
        }
    }
    float beta = 0.f, omb = 0.f;
    if (SKIP) { beta = 1.0f / (1.0f + __expf(-skipB[t])); omb = 1.0f - beta; }
    int node = rowStart + l16;
    bool ok = node < Nrows;
    #pragma unroll
    for (int ct = 0; ct < 2; ++ct) {
        int colBase = ct * 64;
        const unsigned short* wp = Wt + (size_t)(colBase + l16) * 128 + quad * 8;
        #pragma unroll
        for (int c = 0; c < 4; ++c) {
            floatx4 acc = {0, 0, 0, 0};
            #pragma unroll
            for (int kc = 0; kc < 4; ++kc) {
                short8 B = *(const short8*)(wp + (size_t)c * 2048 + kc * 32);
                acc = __builtin_amdgcn_mfma_f32_16x16x32_bf16(B, Afr[kc], acc, 0, 0, 0);
            }
            if (ok) {
                int col0 = colBase + c * 16 + quad * 4;
                float4 bv = *(const float4*)(bias + col0);
                float o0 = acc[0] + bv.x, o1 = acc[1] + bv.y;
                float o2 = acc[2] + bv.z, o3 = acc[3] + bv.w;
                if (SKIP) {
                    uint2 xo = *(const uint2*)(xold + (size_t)node * 128 + col0);
                    o0 = beta * o0 + omb * __uint_as_float(xo.x << 16);
                    o1 = beta * o1 + omb * __uint_as_float(xo.x & 0xffff0000u);
                    o2 = beta * o2 + omb * __uint_as_float(xo.y << 16);
                    o3 = beta * o3 + omb * __uint_as_float(xo.y & 0xffff0000u);
                }
                o0 = fmaxf(o0, 0.f); o1 = fmaxf(o1, 0.f);
                o2 = fmaxf(o2, 0.f); o3 = fmaxf(o3, 0.f);
                uint2 u;
                u.x = (unsigned)f2bf(o0) | ((unsigned)f2bf(o1) << 16);
                u.y = (unsigned)f2bf(o2) | ((unsigned)f2bf(o3) << 16);
                *(uint2*)(out + (size_t)node * 128 + col0) = u;
            }
        }
    }
}

// ---------------- output projection: one GEMM over all 96000 rows ----------
// Operand-swapped: lane stores 4 consecutive f32 cols of one node (float4).
__global__ __launch_bounds__(256) void gemm_out(
    const unsigned short* __restrict__ Abf,
    const unsigned short* __restrict__ Wt,     // [64][128] bf16^T
    const float* __restrict__ bias,
    float* __restrict__ out, int Nrows)
{
    const int wave = threadIdx.x >> 6, lane = threadIdx.x & 63;
    const int quad = lane >> 4, l16 = lane & 15;
    const int rowBase = (blockIdx.x * 4 + wave) * 16;
    if (rowBase >= Nrows) return;
    const unsigned short* wp = Wt + (size_t)l16 * 128 + quad * 8;
    int m = rowBase + l16;
    const unsigned short* ap = Abf + (size_t)((m < Nrows) ? m : 0) * 128 + quad * 8;
    short8 Afr[4];
    #pragma unroll
    for (int kc = 0; kc < 4; ++kc) Afr[kc] = *(const short8*)(ap + kc * 32);
    int node = rowBase + l16;
    bool ok = node < Nrows;
    #pragma unroll
    for (int c = 0; c < 4; ++c) {
        floatx4 acc = {0, 0, 0, 0};
        #pragma unroll
        for (int kc = 0; kc < 4; ++kc) {
            short8 B = *(const short8*)(wp + (size_t)c * 2048 + kc * 32);
            acc = __builtin_amdgcn_mfma_f32_16x16x32_bf16(B, Afr[kc], acc, 0, 0, 0);
        }
        if (ok) {
            int col0 = c * 16 + quad * 4;
            float4 bv = *(const float4*)(bias + col0);
            float4 o;
            o.x = acc[0] + bv.x; o.y = acc[1] + bv.y;
            o.z = acc[2] + bv.z; o.w = acc[3] + bv.w;
            *(float4*)(out + (size_t)node * 64 + col0) = o;
        }
    }
}

// ------------------------- weight prep -------------------------------------
__global__ __launch_bounds__(128) void prep_qpack(
    const float* __restrict__ qw, const float* __restrict__ qb,
    unsigned short* __restrict__ Wpack, float* __restrict__ bpack)
{
    const int pre[3] = {0, 49152, 131072};
    const int preB[3] = {0, 384, 1024};
    int n = threadIdx.x, k = blockIdx.x, t = blockIdx.y, l = blockIdx.z;
    unsigned short* Wp = Wpack + (size_t)l * 180224 + pre[t];
    Wp[(size_t)n * 128 + k] = f2bf(qw[(size_t)(l * 3 + t) * 16384 + (size_t)k * 128 + n]);
    if (k == 0) bpack[l * 1408 + preB[t] + n] = qb[(l * 3 + t) * 128 + n];
}

__global__ __launch_bounds__(128) void fold_rel_pack(
    const float* __restrict__ kw, const float* __restrict__ kb,
    const float* __restrict__ vw, const float* __restrict__ vb,
    const float* __restrict__ a_rel, const float* __restrict__ m_rel,
    unsigned short* __restrict__ Wpack, float* __restrict__ bpack)
{
    const int SIv[4] = {0, 1, 1, 2};
    const int SLOT[4] = {0, 0, 1, 0};
    const int pre[3] = {0, 49152, 131072};
    const int preB[3] = {0, 384, 1024};
    int hf = threadIdx.x, h = hf >> 4, f = hf & 15;
    int c = blockIdx.x, et = blockIdx.y, l = blockIdx.z;
    int si = SIv[et];
    const float* kwp  = kw + (size_t)(l * 3 + si) * 16384;
    const float* vwp  = vw + (size_t)(l * 3 + si) * 16384;
    const float* kbp  = kb + (size_t)(l * 3 + si) * 128;
    const float* vbp  = vb + (size_t)(l * 3 + si) * 128;
    const float* arel = a_rel + (size_t)(l * 4 + et) * 2048;
    const float* mrel = m_rel + (size_t)(l * 4 + et) * 2048;
    float sk = 0.f, sv = 0.f;
    #pragma unroll
    for (int d = 0; d < 16; ++d) {
        float ar = arel[(h * 16 + d) * 16 + f];
        float mr = mrel[(h * 16 + d) * 16 + f];
        sk = fmaf(kwp[c * 128 + h * 16 + d], ar, sk);
        sv = fmaf(vwp[c * 128 + h * 16 + d], mr, sv);
    }
    int rowoff = 128 + 256 * SLOT[et];
    unsigned short* Wp = Wpack + (size_t)l * 180224 + pre[si];
    Wp[(size_t)(rowoff + hf) * 128 + c]       = f2bf(sk);
    Wp[(size_t)(rowoff + 128 + hf) * 128 + c] = f2bf(sv);
    if (c == 0) {
        float bk = 0.f, bvv = 0.f;
        #pragma unroll
        for (int d = 0; d < 16; ++d) {
            bk  = fmaf(kbp[h * 16 + d], arel[(h * 16 + d) * 16 + f], bk);
            bvv = fmaf(vbp[h * 16 + d], mrel[(h * 16 + d) * 16 + f], bvv);
        }
        float* bp = bpack + l * 1408 + preB[si];
        bp[rowoff + hf]       = bk;
        bp[rowoff + 128 + hf] = bvv;
    }
}

__global__ __launch_bounds__(128) void prep_w9(
    const float* __restrict__ lin_w, const float* __restrict__ aw,
    unsigned short* __restrict__ lwt, unsigned short* __restrict__ awt)
{
    int n = threadIdx.x, k = blockIdx.x, mi = blockIdx.y;
    const float* w; unsigned short* wt; int m;
    if (mi < 3) { w = lin_w; wt = lwt; m = mi; }
    else        { w = aw;    wt = awt; m = mi - 3; }
    wt[(size_t)m * 16384 + (size_t)n * 128 + k] =
        f2bf(w[(size_t)m * 16384 + (size_t)k * 128 + n]);
}

__global__ __launch_bounds__(64) void prep_owt(
    const float* __restrict__ ow, unsigned short* __restrict__ owt)
{
    int n = threadIdx.x, k = blockIdx.x;
    owt[(size_t)n * 128 + k] = f2bf(ow[(size_t)k * 64 + n]);
}

// ------------------------- CSR build (fused across edge types) --------------
__global__ __launch_bounds__(256) void hist_all(
    const int* __restrict__ d0, const int* __restrict__ d1,
    const int* __restrict__ d2, const int* __restrict__ d3,
    int* __restrict__ deg4)
{
    const int Ev[4] = {200000, 300000, 200000, 100000};
    int et = blockIdx.y;
    int e = blockIdx.x * 256 + threadIdx.x;
    if (e >= Ev[et]) return;
    const int* d = et == 0 ? d0 : et == 1 ? d1 : et == 2 ? d2 : d3;
    atomicAdd(&deg4[et * 60000 + d[e]], 1);
}

__global__ __launch_bounds__(256) void scan_tile_all(
    const int* __restrict__ deg4,
    int* __restrict__ r0, int* __restrict__ r1, int* __restrict__ r2, int* __restrict__ r3,
    int* __restrict__ tsum4)
{
    const int Ndv[4] = {60000, 60000, 6000, 30000};
    __shared__ int ls[256];
    int et = blockIdx.y;
    int n = Ndv[et];
    const int* deg = deg4 + et * 60000;
    int* rowptr = et == 0 ? r0 : et == 1 ? r1 : et == 2 ? r2 : r3;
    int b = blockIdx.x, tid = threadIdx.x;
    int base = b * 1024 + tid * 4;
    int v0 = 0, v1 = 0, v2 = 0, v3 = 0;
    if (base + 3 < n) {
        int4 t = *(const int4*)(deg + base);
        v0 = t.x; v1 = t.y; v2 = t.z; v3 = t.w;
    } else {
        if (base + 0 < n) v0 = deg[base + 0];
        if (base + 1 < n) v1 = deg[base + 1];
        if (base + 2 < n) v2 = deg[base + 2];
        if (base + 3 < n) v3 = deg[base + 3];
    }
    int s = v0 + v1 + v2 + v3;
    ls[tid] = s;
    __syncthreads();
    #pragma unroll
    for (int off = 1; off < 256; off <<= 1) {
        int t = (tid >= off) ? ls[tid - off] : 0;
        __syncthreads();
        ls[tid] += t;
        __syncthreads();
    }
    int run = ls[tid] - s;
    int o0 = run; run += v0;
    int o1 = run; run += v1;
    int o2 = run; run += v2;
    int o3 = run;
    if (base + 3 < n) {
        *(int4*)(rowptr + base) = make_int4(o0, o1, o2, o3);
    } else {
        if (base + 0 < n) rowptr[base + 0] = o0;
        if (base + 1 < n) rowptr[base + 1] = o1;
        if (base + 2 < n) rowptr[base + 2] = o2;
    }
    if (tid == 255) tsum4[et * 64 + b] = ls[255];
}

__global__ __launch_bounds__(64) void scan_tsum_all(
    int* __restrict__ tsum4,
    int* __restrict__ r0, int* __restrict__ r1, int* __restrict__ r2, int* __restrict__ r3)
{
    const int Ndv[4] = {60000, 60000, 6000, 30000};
    int et = blockIdx.x;
    int n = Ndv[et];
    int nt = (n + 1023) >> 10;
    int* tileSum = tsum4 + et * 64;
    int* rowptr = et == 0 ? r0 : et == 1 ? r1 : et == 2 ? r2 : r3;
    int tid = threadIdx.x;
    int v = (tid < nt) ? tileSum[tid] : 0;
    int orig = v;
    #pragma unroll
    for (int off = 1; off < 64; off <<= 1) {
        int t = __shfl_up(v, off);
        if (tid >= off) v += t;
    }
    if (tid < nt) tileSum[tid] = v - orig;
    if (tid == nt - 1) rowptr[n] = v;
}

__global__ __launch_bounds__(256) void scan_add_all(
    int* __restrict__ r0, int* __restrict__ r1, int* __restrict__ r2, int* __restrict__ r3,
    const int* __restrict__ tsum4)
{
    const int Ndv[4] = {60000, 60000, 6000, 30000};
    int et = blockIdx.y;
    int n = Ndv[et];
    int* rowptr = et == 0 ? r0 : et == 1 ? r1 : et == 2 ? r2 : r3;
    int i = blockIdx.x * 256 + threadIdx.x;
    if (i < n) rowptr[i] += tsum4[et * 64 + (i >> 10)];
}

__global__ __launch_bounds__(256) void fill_all(
    const int* __restrict__ s0, const int* __restrict__ d0,
    const int* __restrict__ s1, const int* __restrict__ d1,
    const int* __restrict__ s2, const int* __restrict__ d2,
    const int* __restrict__ s3, const int* __restrict__ d3,
    const int* __restrict__ r0, const int* __restrict__ r1,
    const int* __restrict__ r2, const int* __restrict__ r3,
    int* __restrict__ deg4,
    int* __restrict__ c0, int* __restrict__ c1, int* __restrict__ c2, int* __restrict__ c3)
{
    const int Ev[4] = {200000, 300000, 200000, 100000};
    int et = blockIdx.y;
    int e = blockIdx.x * 256 + threadIdx.x;
    if (e >= Ev[et]) return;
    const int* src = et == 0 ? s0 : et == 1 ? s1 : et == 2 ? s2 : s3;
    const int* dst = et == 0 ? d0 : et == 1 ? d1 : et == 2 ? d2 : d3;
    const int* rowptr = et == 0 ? r0 : et == 1 ? r1 : et == 2 ? r2 : r3;
    int* csr = et == 0 ? c0 : et == 1 ? c1 : et == 2 ? c2 : c3;
    int d = dst[e];
    int pos = atomicAdd(&deg4[et * 60000 + d], 1);
    csr[rowptr[d] + pos] = src[e];
}

// --------------- merged gather-side attention (all 4 edge types) ------------
// Software-pipelined: edge j+1's K/V loads issue before edge j's compute.
// Defer-max (THR=8): o-rescale only when the running max grows by >8;
// exact math (o and l always carry the common factor exp(-m)).
__device__ __forceinline__ void attn_run(
    const int* __restrict__ csr, int beg, int end,
    const unsigned short* __restrict__ kbase, int ld,
    const float* qf, float ph, float& m, float& l, float* o)
{
    if (beg >= end) return;
    int s = csr[beg];
    const uint4* kp = (const uint4*)(kbase + (size_t)s * ld);
    uint4 ku0 = kp[0], ku1 = kp[1];
    uint4 vu0 = kp[16], vu1 = kp[17];       // mv at +128 shorts
    for (int j = beg; j < end; ++j) {
        uint4 nk0 = ku0, nk1 = ku1, nv0 = vu0, nv1 = vu1;
        if (j + 1 < end) {                  // prefetch next edge
            int sn = csr[j + 1];
            const uint4* np = (const uint4*)(kbase + (size_t)sn * ld);
            nk0 = np[0]; nk1 = np[1]; nv0 = np[16]; nv1 = np[17];
        }
        float kf[16], vf[16];
        up8(ku0, kf); up8(ku1, kf + 8);
        up8(vu0, vf); up8(vu1, vf + 8);
        float a = 0.f;
        #pragma unroll
        for (int i = 0; i < 16; ++i) a = fmaf(qf[i], kf[i], a);
        a *= ph;
        float d = a - m;
        if (d > 8.f) {                      // rare after first edge
            float sc = __expf(-d);
            l *= sc;
            #pragma unroll
            for (int i = 0; i < 16; ++i) o[i] *= sc;
            m = a; d = 0.f;
        }
        float w = __expf(d);                // d <= 8 -> w <= e^8
        l += w;
        #pragma unroll
        for (int i = 0; i < 16; ++i) o[i] = fmaf(w, vf[i], o[i]);
        ku0 = nk0; ku1 = nk1; vu0 = nv0; vu1 = nv1;
    }
}

// grid: [0,1875) road(et0+et1 serial) / [1875,2625) region(et2, 4-way split) /
//       [2625,3563) poi(et3)
__global__ __launch_bounds__(256) void agg_all(
    const int* __restrict__ rp0, const int* __restrict__ cs0,
    const int* __restrict__ rp1, const int* __restrict__ cs1,
    const int* __restrict__ rp2, const int* __restrict__ cs2,
    const int* __restrict__ rp3, const int* __restrict__ cs3,
    const unsigned short* __restrict__ P0, const unsigned short* __restrict__ P1,
    const unsigned short* __restrict__ P2,
    const float* __restrict__ prl,      // p_rel + l*32
    unsigned short* __restrict__ num)
{
    int gb = blockIdx.x, tid = threadIdx.x;
    float qf[16], o[16], r[16];
    if (gb < 1875) {
        // ---- road: et0 (poi src) + et1 (road src), separate softmaxes ----
        int t = gb * 256 + tid;            // < 480000 exactly
        int node = t >> 3, h = t & 7;
        const uint4* qp = (const uint4*)(P1 + (size_t)node * 640 + h * 16);
        up8(qp[0], qf); up8(qp[1], qf + 8);
        float m0 = -INFINITY, l0 = 0.f;
        #pragma unroll
        for (int i = 0; i < 16; ++i) o[i] = 0.f;
        attn_run(cs0, rp0[node], rp0[node + 1], P0 + 128 + h * 16, 384,
                 qf, prl[h] * 0.25f, m0, l0, o);
        float i0 = 1.f / (l0 + 1e-16f);
        #pragma unroll
        for (int i = 0; i < 16; ++i) { r[i] = i0 * o[i]; o[i] = 0.f; }
        float m1 = -INFINITY, l1 = 0.f;
        attn_run(cs1, rp1[node], rp1[node + 1], P1 + 128 + h * 16, 640,
                 qf, prl[8 + h] * 0.25f, m1, l1, o);
        float i1 = 1.f / (l1 + 1e-16f);
        #pragma unroll
        for (int i = 0; i < 16; ++i) r[i] += i1 * o[i];
        uint4* np = (uint4*)(num + (size_t)(30000 + node) * 128 + h * 16);
        np[0] = pk8(r); np[1] = pk8(r + 8);
    } else if (gb < 2625) {
        // ---- region: et2 (road src), 4-way edge split + shuffle merge ----
        int t = (gb - 1875) * 256 + tid;   // < 192000 exactly
        int node = t >> 5, h = t & 7, sub = (t >> 3) & 3;
        int beg0 = rp2[node], end0 = rp2[node + 1];
        int n = end0 - beg0;
        int beg = beg0 + ((n * sub) >> 2);
        int end = beg0 + ((n * (sub + 1)) >> 2);
        const uint4* qp = (const uint4*)(P2 + (size_t)node * 384 + h * 16);
        up8(qp[0], qf); up8(qp[1], qf + 8);
        float m = -INFINITY, l = 0.f;
        #pragma unroll
        for (int i = 0; i < 16; ++i) o[i] = 0.f;
        attn_run(cs2, beg, end, P1 + 384 + h * 16, 640,
                 qf, prl[16 + h] * 0.25f, m, l, o);
        #pragma unroll
        for (int st = 8; st <= 16; st <<= 1) {
            float mp = __shfl_xor(m, st);
            float lp = __shfl_xor(l, st);
            float mn = fmaxf(m, mp);
            float sc  = (l  > 0.f) ? __expf(m  - mn) : 0.f;
            float scp = (lp > 0.f) ? __expf(mp - mn) : 0.f;
            l = l * sc + lp * scp;
            #pragma unroll
            for (int i = 0; i < 16; ++i) {
                float op = __shfl_xor(o[i], st);
                o[i] = o[i] * sc + op * scp;
            }
            m = mn;
        }
        if (sub) return;
        float inv = 1.f / (l + 1e-16f);
        #pragma unroll
        for (int i = 0; i < 16; ++i) r[i] = inv * o[i];
        uint4* np = (uint4*)(num + (size_t)(90000 + node) * 128 + h * 16);
        np[0] = pk8(r); np[1] = pk8(r + 8);
    } else {
        // ---- poi: et3 (region src) ----
        int t = (gb - 2625) * 256 + tid;
        if (t >= 240000) return;
        int node = t >> 3, h = t & 7;
        const uint4* qp = (const uint4*)(P0 + (size_t)node * 384 + h * 16);
        up8(qp[0], qf); up8(qp[1], qf + 8);
        float m = -INFINITY, l = 0.f;
        #pragma unroll
        for (int i = 0; i < 16; ++i) o[i] = 0.f;
        attn_run(cs3, rp3[node], rp3[node + 1], P2 + 128 + h * 16, 384,
                 qf, prl[24 + h] * 0.25f, m, l, o);
        float inv = 1.f / (l + 1e-16f);
        #pragma unroll
        for (int i = 0; i < 16; ++i) r[i] = inv * o[i];
        uint4* np = (uint4*)(num + (size_t)node * 128 + h * 16);
        np[0] = pk8(r); np[1] = pk8(r + 8);
    }
}

extern "C" void kernel_launch(void* const* d_in, const int* in_sizes, int n_in,
                              void* d_out, int out_size, void* d_ws, size_t ws_size,
                              hipStream_t stream)
{
    (void)in_sizes; (void)n_in; (void)out_size; (void)ws_size;

    const float* xin[3] = {(const float*)d_in[0], (const float*)d_in[1], (const float*)d_in[2]};
    const int* esrc[4] = {(const int*)d_in[3], (const int*)d_in[5], (const int*)d_in[7], (const int*)d_in[9]};
    const int* edst[4] = {(const int*)d_in[4], (const int*)d_in[6], (const int*)d_in[8], (const int*)d_in[10]};
    const float* lin_w = (const float*)d_in[11];
    const float* lin_b = (const float*)d_in[12];
    const float* kw = (const float*)d_in[13];
    const float* qw = (const float*)d_in[14];
    const float* vw = (const float*)d_in[15];
    const float* aw = (const float*)d_in[16];
    const float* kb = (const float*)d_in[17];
    const float* qb = (const float*)d_in[18];
    const float* vb = (const float*)d_in[19];
    const float* ab = (const float*)d_in[20];
    const float* a_rel = (const float*)d_in[21];
    const float* m_rel = (const float*)d_in[22];
    const float* p_rel = (const float*)d_in[23];
    const float* skip  = (const float*)d_in[24];
    const float* out_w = (const float*)d_in[25];
    const float* out_b = (const float*)d_in[26];

    // workspace (float-index units; ~39.9M floats = 160 MB)
    float* ws = (float*)d_ws;
    unsigned short* num   = (unsigned short*)ws;                // 12,288,000 h
    unsigned short* xs_bf = (unsigned short*)(ws + 6144000);    // 12,288,000 h
    unsigned short* proj  = (unsigned short*)(ws + 12288000);   // 52,224,000 h
    unsigned short* Wpack = (unsigned short*)(ws + 38400000);   // 360,448 h
    unsigned short* lwt   = (unsigned short*)(ws + 38580224);   // 49,152 h
    unsigned short* awt   = (unsigned short*)(ws + 38604800);   // 98,304 h
    unsigned short* owt   = (unsigned short*)(ws + 38653952);   // 8,192 h
    float*          bpack = ws + 38658048;                      // 2,816 f
    int*            deg4  = (int*)(ws + 38660864);              // 240,000
    int*            tsum4 = (int*)(ws + 38900864);              // 256
    int* rp[4];
    rp[0] = (int*)(ws + 38901120);                              // 60,008
    rp[1] = (int*)(ws + 38961128);
    rp[2] = (int*)(ws + 39021136);                              // 6,008
    rp[3] = (int*)(ws + 39027144);                              // 30,008
    int* cs[4];
    cs[0] = (int*)(ws + 39057152);                              // 200,000
    cs[1] = (int*)(ws + 39257152);                              // 300,000
    cs[2] = (int*)(ws + 39557152);                              // 200,000
    cs[3] = (int*)(ws + 39757152);                              // 100,000

    unsigned short* P[3];
    P[0] = proj;
    P[1] = proj + (size_t)30000 * 384;
    P[2] = proj + (size_t)30000 * 384 + (size_t)60000 * 640;

    dim3 blk(256);

    // ---- CSR build, fused across edge types ----
    hipMemsetAsync(deg4, 0, 960000, stream);
    hist_all<<<dim3(1172, 4), blk, 0, stream>>>(edst[0], edst[1], edst[2], edst[3], deg4);
    scan_tile_all<<<dim3(59, 4), blk, 0, stream>>>(deg4, rp[0], rp[1], rp[2], rp[3], tsum4);
    scan_tsum_all<<<dim3(4), dim3(64), 0, stream>>>(tsum4, rp[0], rp[1], rp[2], rp[3]);
    scan_add_all<<<dim3(235, 4), blk, 0, stream>>>(rp[0], rp[1], rp[2], rp[3], tsum4);
    hipMemsetAsync(deg4, 0, 960000, stream);
    fill_all<<<dim3(1172, 4), blk, 0, stream>>>(
        esrc[0], edst[0], esrc[1], edst[1], esrc[2], edst[2], esrc[3], edst[3],
        rp[0], rp[1], rp[2], rp[3], deg4, cs[0], cs[1], cs[2], cs[3]);

    // ---- weight prep ----
    prep_qpack<<<dim3(128, 3, 2), dim3(128), 0, stream>>>(qw, qb, Wpack, bpack);
    fold_rel_pack<<<dim3(128, 4, 2), dim3(128), 0, stream>>>(
        kw, kb, vw, vb, a_rel, m_rel, Wpack, bpack);
    prep_w9<<<dim3(128, 9), dim3(128), 0, stream>>>(lin_w, aw, lwt, awt);
    prep_owt<<<dim3(128), dim3(64), 0, stream>>>(out_w, owt);

    // ---- input linear + relu -> xs_bf (fused across types) ----
    gemm_node<true, false, false><<<dim3(1501), blk, 0, stream>>>(
        xin[0], xin[1], xin[2], lwt, lin_b, nullptr, nullptr, xs_bf);

    for (int l = 0; l < 2; ++l) {
        // packed projection per node type: [q | ka|mv ...], one fused launch
        gemm_proj_all<<<dim3(3191), blk, 0, stream>>>(
            xs_bf, Wpack + (size_t)l * 180224, bpack + l * 1408, proj);

        // merged aggregation: all 4 edge types in one launch
        agg_all<<<dim3(3563), blk, 0, stream>>>(
            rp[0], cs[0], rp[1], cs[1], rp[2], cs[2], rp[3], cs[3],
            P[0], P[1], P[2], p_rel + (size_t)l * 32, num);

        // node update (fused across types)
        gemm_node<false, true, true><<<dim3(1501), blk, 0, stream>>>(
            num, num + (size_t)30000 * 128, num + (size_t)90000 * 128,
            awt + (size_t)l * 3 * 16384, ab + (size_t)l * 3 * 128,
            xs_bf, skip + l * 3, xs_bf);
    }

    // ---- output projection: single GEMM over all 96000 rows ----
    gemm_out<<<dim3(1500), blk, 0, stream>>>(
        xs_bf, owt, out_b, (float*)d_out, 96000);
}

// Round 3
// 580.568 us; speedup vs baseline: 1.1536x; 1.1039x over previous
//
#include <hip/hip_runtime.h>
#include <cstddef>
#include <cstdint>

// ---------------------------------------------------------------------------
// HGT forward for MI355X. C=128, H=8, D=16, OUT=64, L=2
//   NN = {30000, 60000, 6000}, NE = {200000, 300000, 200000, 100000}
//   ETS = {(0,1),(1,1),(1,2),(2,0)}
// Round-12 changes:
//  * All GEMMs restructured to W-resident-in-VGPR row-streaming: each wave
//    loads its W panel ONCE (proj: 2 tiles=128 VGPR; node: full 128x128;
//    out: 128x64), then streams 16-row A panels with 1-deep prefetch.
//    Old structure re-loaded W per tile from L2 (~300cy) with only ~155cy
//    of MFMA to hide it -> latency-bound at 23% HBM / 10% VALU / 6% MFMA.
//  * __launch_bounds__(256,2) pins allocation at <=256 VGPR (2 waves/SIMD).
// ---------------------------------------------------------------------------

typedef __attribute__((ext_vector_type(8))) short short8;   // 8 x bf16
typedef __attribute__((ext_vector_type(4))) float floatx4;

__device__ __forceinline__ float gelu_fast(float x) {
    // 0.5x(1+tanh(c(x+0.044715x^3))) == x*sigmoid(2c x (1+0.044715x^2))
    float u = 1.5957691216057308f * x * (1.0f + 0.044715f * x * x);
    return x / (1.0f + __expf(-u));
}

__device__ __forceinline__ unsigned short f2bf(float f) {   // RNE fp32->bf16
    unsigned u = __float_as_uint(f);
    u += 0x7fffu + ((u >> 16) & 1);
    return (unsigned short)(u >> 16);
}

__device__ __forceinline__ float bf2f(unsigned short h) {
    return __uint_as_float((unsigned)h << 16);
}

__device__ __forceinline__ void up8(uint4 u, float* f) {    // 8 bf16 -> 8 fp32
    f[0] = __uint_as_float(u.x << 16); f[1] = __uint_as_float(u.x & 0xffff0000u);
    f[2] = __uint_as_float(u.y << 16); f[3] = __uint_as_float(u.y & 0xffff0000u);
    f[4] = __uint_as_float(u.z << 16); f[5] = __uint_as_float(u.z & 0xffff0000u);
    f[6] = __uint_as_float(u.w << 16); f[7] = __uint_as_float(u.w & 0xffff0000u);
}

__device__ __forceinline__ uint4 pk8(const float* f) {      // 8 fp32 -> 8 bf16
    uint4 u;
    u.x = (unsigned)f2bf(f[0]) | ((unsigned)f2bf(f[1]) << 16);
    u.y = (unsigned)f2bf(f[2]) | ((unsigned)f2bf(f[3]) << 16);
    u.z = (unsigned)f2bf(f[4]) | ((unsigned)f2bf(f[5]) << 16);
    u.w = (unsigned)f2bf(f[6]) | ((unsigned)f2bf(f[7]) << 16);
    return u;
}

// ---------------- W-resident streaming MFMA GEMM (packed proj) -------------
// Frag layouts (verified m89): operand-swapped mfma(Wfrag, Xfrag) ->
// D[outcol=quad*4+reg][node=l16]; lane stores 4 consecutive bf16 cols of one
// node as one uint2 (8B).
// Each wave: holds W for one 128-col pair (2 tiles, 128 VGPR), streams
// 16-row A panels (block covers 64 rows/panel, 8 panels) with 1-deep
// prefetch. Blocks: road [0,590)=5cp x 118 / poi [590,767)=3cp x 59 /
// region [767,803)=3cp x 12.
__global__ __launch_bounds__(256, 2) void gemm_proj_all(
    const unsigned short* __restrict__ xs_bf,
    const unsigned short* __restrict__ Wl,     // Wpack + l*180224
    const float* __restrict__ bl,              // bpack + l*1408
    unsigned short* __restrict__ proj)
{
    const int    NN_[3]  = {30000, 60000, 6000};
    const int    NPAN[3] = {469, 938, 94};
    const int    OFFr[3] = {0, 30000, 90000};
    const int    WOFF[3] = {0, 49152, 131072};
    const int    BOFF[3] = {0, 384, 1024};
    const size_t POFF[3] = {0, 11520000u, 49920000u};
    const int    LDO[3]  = {384, 640, 384};

    int b = blockIdx.x, t, cp, rb;
    if (b < 590)      { t = 1; cp = b / 118; rb = b - cp * 118; }
    else if (b < 767) { int lb = b - 590; t = 0; cp = lb / 59; rb = lb - cp * 59; }
    else              { int lb = b - 767; t = 2; cp = lb / 12; rb = lb - cp * 12; }
    int p0 = rb * 8, p1 = p0 + 8;
    if (p1 > NPAN[t]) p1 = NPAN[t];

    const unsigned short* Abf = xs_bf + (size_t)OFFr[t] * 128;
    const unsigned short* Wt  = Wl + WOFF[t];
    const float* bias = bl + BOFF[t] + cp * 128;
    unsigned short* outbf = proj + POFF[t];
    const int ldo = LDO[t], Nrows = NN_[t];

    const int wave = threadIdx.x >> 6, lane = threadIdx.x & 63;
    const int quad = lane >> 4, l16 = lane & 15;

    // W resident: 2 tiles x 64 cols, [T][c][kc]
    short8 B[2][4][4];
    {
        const unsigned short* wb = Wt + (size_t)(cp * 128 + l16) * 128 + quad * 8;
        #pragma unroll
        for (int T = 0; T < 2; ++T)
            #pragma unroll
            for (int c = 0; c < 4; ++c)
                #pragma unroll
                for (int kc = 0; kc < 4; ++kc)
                    B[T][c][kc] = *(const short8*)(wb + (size_t)(T * 64 + c * 16) * 128 + kc * 32);
    }
    float4 bv[2][4];
    #pragma unroll
    for (int T = 0; T < 2; ++T)
        #pragma unroll
        for (int c = 0; c < 4; ++c)
            bv[T][c] = *(const float4*)(bias + T * 64 + c * 16 + quad * 4);

    short8 Acur[4];
    {
        int m = p0 * 64 + wave * 16 + l16; if (m >= Nrows) m = Nrows - 1;
        const unsigned short* ap = Abf + (size_t)m * 128 + quad * 8;
        #pragma unroll
        for (int kc = 0; kc < 4; ++kc) Acur[kc] = *(const short8*)(ap + kc * 32);
    }
    for (int p = p0; p < p1; ++p) {
        short8 Anx[4];
        {
            int m = (p + 1) * 64 + wave * 16 + l16; if (m >= Nrows) m = Nrows - 1;
            const unsigned short* ap = Abf + (size_t)m * 128 + quad * 8;
            #pragma unroll
            for (int kc = 0; kc < 4; ++kc) Anx[kc] = *(const short8*)(ap + kc * 32);
        }
        floatx4 acc[2][4];
        #pragma unroll
        for (int T = 0; T < 2; ++T)
            #pragma unroll
            for (int c = 0; c < 4; ++c) acc[T][c] = (floatx4){0.f, 0.f, 0.f, 0.f};
        #pragma unroll
        for (int kc = 0; kc < 4; ++kc)
            #pragma unroll
            for (int T = 0; T < 2; ++T)
                #pragma unroll
                for (int c = 0; c < 4; ++c)
                    acc[T][c] = __builtin_amdgcn_mfma_f32_16x16x32_bf16(B[T][c][kc], Acur[kc], acc[T][c], 0, 0, 0);
        int node = p * 64 + wave * 16 + l16;
        if (node < Nrows) {
            unsigned short* op = outbf + (size_t)node * ldo + cp * 128 + quad * 4;
            #pragma unroll
            for (int T = 0; T < 2; ++T)
                #pragma unroll
                for (int c = 0; c < 4; ++c) {
                    uint2 u;
                    u.x = (unsigned)f2bf(acc[T][c][0] + bv[T][c].x) |
                          ((unsigned)f2bf(acc[T][c][1] + bv[T][c].y) << 16);
                    u.y = (unsigned)f2bf(acc[T][c][2] + bv[T][c].z) |
                          ((unsigned)f2bf(acc[T][c][3] + bv[T][c].w) << 16);
                    *(uint2*)(op + T * 64 + c * 16) = u;
                }
        }
        #pragma unroll
        for (int kc = 0; kc < 4; ++kc) Acur[kc] = Anx[kc];
    }
}

// ---------------- fused-by-type node GEMM (input linear / node update) -----
// Full 128x128 W resident per wave (128 VGPR); streams 16-row panels with
// 1-deep prefetch; 2 panels/block. Blocks: poi [0,235) / road [235,704) /
// region [704,751).
template<bool AF32, bool GIN, bool SKIP>
__global__ __launch_bounds__(256, 2) void gemm_node(
    const void* __restrict__ a0v, const void* __restrict__ a1v, const void* __restrict__ a2v,
    const unsigned short* __restrict__ WtB, const float* __restrict__ biasB,
    const unsigned short* __restrict__ xoldB, const float* __restrict__ skipB,
    unsigned short* __restrict__ outB)
{
    const int TN[3]   = {30000, 60000, 6000};
    const int NPAN[3] = {469, 938, 94};
    const int TOFF[3] = {0, 30000, 90000};
    int b = blockIdx.x, t, rb;
    if (b < 235)      { t = 0; rb = b; }
    else if (b < 704) { t = 1; rb = b - 235; }
    else              { t = 2; rb = b - 704; }
    int p0 = rb * 2, p1 = p0 + 2;
    if (p1 > NPAN[t]) p1 = NPAN[t];
    int Nrows = TN[t];
    const void* av = (t == 0) ? a0v : (t == 1) ? a1v : a2v;
    const unsigned short* xold = xoldB + (size_t)TOFF[t] * 128;
    unsigned short* out = outB + (size_t)TOFF[t] * 128;

    const int wave = threadIdx.x >> 6, lane = threadIdx.x & 63;
    const int quad = lane >> 4, l16 = lane & 15;

    // full W resident: [c=0..7][kc]
    short8 B[8][4];
    {
        const unsigned short* wb = WtB + (size_t)t * 16384 + (size_t)l16 * 128 + quad * 8;
        #pragma unroll
        for (int c = 0; c < 8; ++c)
            #pragma unroll
            for (int kc = 0; kc < 4; ++kc)
                B[c][kc] = *(const short8*)(wb + (size_t)c * 2048 + kc * 32);
    }
    float beta = 0.f, omb = 0.f;
    if (SKIP) { beta = 1.0f / (1.0f + __expf(-skipB[t])); omb = 1.0f - beta; }

    short8 Acur[4];
    {
        int m = p0 * 64 + wave * 16 + l16; if (m >= Nrows) m = Nrows - 1;
        size_t base = (size_t)m * 128 + quad * 8;
        #pragma unroll
        for (int kc = 0; kc < 4; ++kc) {
            if (AF32) {
                const float* ap = (const float*)av + base;
                float4 f0 = *(const float4*)(ap + kc * 32);
                float4 f1 = *(const float4*)(ap + kc * 32 + 4);
                float af[8] = {f0.x, f0.y, f0.z, f0.w, f1.x, f1.y, f1.z, f1.w};
                short8 a;
                #pragma unroll
                for (int i = 0; i < 8; ++i) a[i] = (short)f2bf(af[i]);
                Acur[kc] = a;
            } else if (GIN) {
                const unsigned short* ap = (const unsigned short*)av + base;
                short8 a8 = *(const short8*)(ap + kc * 32);
                short8 a;
                #pragma unroll
                for (int i = 0; i < 8; ++i)
                    a[i] = (short)f2bf(gelu_fast(bf2f((unsigned short)a8[i])));
                Acur[kc] = a;
            } else {
                const unsigned short* ap = (const unsigned short*)av + base;
                Acur[kc] = *(const short8*)(ap + kc * 32);
            }
        }
    }
    for (int p = p0; p < p1; ++p) {
        // prefetch next panel raw
        float4 Fnx[4][2];
        short8 Snx[4];
        {
            int m = (p + 1) * 64 + wave * 16 + l16; if (m >= Nrows) m = Nrows - 1;
            size_t base = (size_t)m * 128 + quad * 8;
            #pragma unroll
            for (int kc = 0; kc < 4; ++kc) {
                if (AF32) {
                    const float* ap = (const float*)av + base;
                    Fnx[kc][0] = *(const float4*)(ap + kc * 32);
                    Fnx[kc][1] = *(const float4*)(ap + kc * 32 + 4);
                } else {
                    const unsigned short* ap = (const unsigned short*)av + base;
                    Snx[kc] = *(const short8*)(ap + kc * 32);
                }
            }
        }
        int node = p * 64 + wave * 16 + l16;
        int ncl = (node < Nrows) ? node : (Nrows - 1);
        // prefetch skip-connection values before the MFMA block
        uint2 xo[8];
        if (SKIP) {
            #pragma unroll
            for (int c = 0; c < 8; ++c)
                xo[c] = *(const uint2*)(xold + (size_t)ncl * 128 + c * 16 + quad * 4);
        }
        floatx4 acc[8];
        #pragma unroll
        for (int c = 0; c < 8; ++c) acc[c] = (floatx4){0.f, 0.f, 0.f, 0.f};
        #pragma unroll
        for (int kc = 0; kc < 4; ++kc)
            #pragma unroll
            for (int c = 0; c < 8; ++c)
                acc[c] = __builtin_amdgcn_mfma_f32_16x16x32_bf16(B[c][kc], Acur[kc], acc[c], 0, 0, 0);
        if (node < Nrows) {
            #pragma unroll
            for (int c = 0; c < 8; ++c) {
                int col0 = c * 16 + quad * 4;
                float4 bv = *(const float4*)(biasB + t * 128 + col0);
                float o0 = acc[c][0] + bv.x, o1 = acc[c][1] + bv.y;
                float o2 = acc[c][2] + bv.z, o3 = acc[c][3] + bv.w;
                if (SKIP) {
                    o0 = beta * o0 + omb * __uint_as_float(xo[c].x << 16);
                    o1 = beta * o1 + omb * __uint_as_float(xo[c].x & 0xffff0000u);
                    o2 = beta * o2 + omb * __uint_as_float(xo[c].y << 16);
                    o3 = beta * o3 + omb * __uint_as_float(xo[c].y & 0xffff0000u);
                }
                o0 = fmaxf(o0, 0.f); o1 = fmaxf(o1, 0.f);
                o2 = fmaxf(o2, 0.f); o3 = fmaxf(o3, 0.f);
                uint2 u;
                u.x = (unsigned)f2bf(o0) | ((unsigned)f2bf(o1) << 16);
                u.y = (unsigned)f2bf(o2) | ((unsigned)f2bf(o3) << 16);
                *(uint2*)(out + (size_t)node * 128 + col0) = u;
            }
        }
        // transform next -> Acur (the vmcnt wait lands here, after the MFMAs)
        #pragma unroll
        for (int kc = 0; kc < 4; ++kc) {
            if (AF32) {
                float af[8] = {Fnx[kc][0].x, Fnx[kc][0].y, Fnx[kc][0].z, Fnx[kc][0].w,
                               Fnx[kc][1].x, Fnx[kc][1].y, Fnx[kc][1].z, Fnx[kc][1].w};
                short8 a;
                #pragma unroll
                for (int i = 0; i < 8; ++i) a[i] = (short)f2bf(af[i]);
                Acur[kc] = a;
            } else if (GIN) {
                short8 a;
                #pragma unroll
                for (int i = 0; i < 8; ++i)
                    a[i] = (short)f2bf(gelu_fast(bf2f((unsigned short)Snx[kc][i])));
                Acur[kc] = a;
            } else {
                Acur[kc] = Snx[kc];
            }
        }
    }
}

// ---------------- output projection: one GEMM over all 96000 rows ----------
// W-resident (128x64 = 64 VGPR), 4 panels/block, float4 stores.
__global__ __launch_bounds__(256, 3) void gemm_out(
    const unsigned short* __restrict__ Abf,
    const unsigned short* __restrict__ Wt,     // [64][128] bf16^T
    const float* __restrict__ bias,
    float* __restrict__ out, int Nrows)
{
    const int wave = threadIdx.x >> 6, lane = threadIdx.x & 63;
    const int quad = lane >> 4, l16 = lane & 15;
    int p0 = blockIdx.x * 4, p1 = p0 + 4;

    short8 B[4][4];
    {
        const unsigned short* wb = Wt + (size_t)l16 * 128 + quad * 8;
        #pragma unroll
        for (int c = 0; c < 4; ++c)
            #pragma unroll
            for (int kc = 0; kc < 4; ++kc)
                B[c][kc] = *(const short8*)(wb + (size_t)c * 2048 + kc * 32);
    }
    float4 bv[4];
    #pragma unroll
    for (int c = 0; c < 4; ++c) bv[c] = *(const float4*)(bias + c * 16 + quad * 4);

    short8 Acur[4];
    {
        int m = p0 * 64 + wave * 16 + l16; if (m >= Nrows) m = Nrows - 1;
        const unsigned short* ap = Abf + (size_t)m * 128 + quad * 8;
        #pragma unroll
        for (int kc = 0; kc < 4; ++kc) Acur[kc] = *(const short8*)(ap + kc * 32);
    }
    for (int p = p0; p < p1; ++p) {
        short8 Anx[4];
        {
            int m = (p + 1) * 64 + wave * 16 + l16; if (m >= Nrows) m = Nrows - 1;
            const unsigned short* ap = Abf + (size_t)m * 128 + quad * 8;
            #pragma unroll
            for (int kc = 0; kc < 4; ++kc) Anx[kc] = *(const short8*)(ap + kc * 32);
        }
        floatx4 acc[4];
        #pragma unroll
        for (int c = 0; c < 4; ++c) acc[c] = (floatx4){0.f, 0.f, 0.f, 0.f};
        #pragma unroll
        for (int kc = 0; kc < 4; ++kc)
            #pragma unroll
            for (int c = 0; c < 4; ++c)
                acc[c] = __builtin_amdgcn_mfma_f32_16x16x32_bf16(B[c][kc], Acur[kc], acc[c], 0, 0, 0);
        int node = p * 64 + wave * 16 + l16;
        if (node < Nrows) {
            #pragma unroll
            for (int c = 0; c < 4; ++c) {
                float4 o;
                o.x = acc[c][0] + bv[c].x; o.y = acc[c][1] + bv[c].y;
                o.z = acc[c][2] + bv[c].z; o.w = acc[c][3] + bv[c].w;
                *(float4*)(out + (size_t)node * 64 + c * 16 + quad * 4) = o;
            }
        }
        #pragma unroll
        for (int kc = 0; kc < 4; ++kc) Acur[kc] = Anx[kc];
    }
}

// ------------------------- weight prep -------------------------------------
__global__ __launch_bounds__(128) void prep_qpack(
    const float* __restrict__ qw, const float* __restrict__ qb,
    unsigned short* __restrict__ Wpack, float* __restrict__ bpack)
{
    const int pre[3] = {0, 49152, 131072};
    const int preB[3] = {0, 384, 1024};
    int n = threadIdx.x, k = blockIdx.x, t = blockIdx.y, l = blockIdx.z;
    unsigned short* Wp = Wpack + (size_t)l * 180224 + pre[t];
    Wp[(size_t)n * 128 + k] = f2bf(qw[(size_t)(l * 3 + t) * 16384 + (size_t)k * 128 + n]);
    if (k == 0) bpack[l * 1408 + preB[t] + n] = qb[(l * 3 + t) * 128 + n];
}

__global__ __launch_bounds__(128) void fold_rel_pack(
    const float* __restrict__ kw, const float* __restrict__ kb,
    const float* __restrict__ vw, const float* __restrict__ vb,
    const float* __restrict__ a_rel, const float* __restrict__ m_rel,
    unsigned short* __restrict__ Wpack, float* __restrict__ bpack)
{
    const int SIv[4] = {0, 1, 1, 2};
    const int SLOT[4] = {0, 0, 1, 0};
    const int pre[3] = {0, 49152, 131072};
    const int preB[3] = {0, 384, 1024};
    int hf = threadIdx.x, h = hf >> 4, f = hf & 15;
    int c = blockIdx.x, et = blockIdx.y, l = blockIdx.z;
    int si = SIv[et];
    const float* kwp  = kw + (size_t)(l * 3 + si) * 16384;
    const float* vwp  = vw + (size_t)(l * 3 + si) * 16384;
    const float* kbp  = kb + (size_t)(l * 3 + si) * 128;
    const float* vbp  = vb + (size_t)(l * 3 + si) * 128;
    const float* arel = a_rel + (size_t)(l * 4 + et) * 2048;
    const float* mrel = m_rel + (size_t)(l * 4 + et) * 2048;
    float sk = 0.f, sv = 0.f;
    #pragma unroll
    for (int d = 0; d < 16; ++d) {
        float ar = arel[(h * 16 + d) * 16 + f];
        float mr = mrel[(h * 16 + d) * 16 + f];
        sk = fmaf(kwp[c * 128 + h * 16 + d], ar, sk);
        sv = fmaf(vwp[c * 128 + h * 16 + d], mr, sv);
    }
    int rowoff = 128 + 256 * SLOT[et];
    unsigned short* Wp = Wpack + (size_t)l * 180224 + pre[si];
    Wp[(size_t)(rowoff + hf) * 128 + c]       = f2bf(sk);
    Wp[(size_t)(rowoff + 128 + hf) * 128 + c] = f2bf(sv);
    if (c == 0) {
        float bk = 0.f, bvv = 0.f;
        #pragma unroll
        for (int d = 0; d < 16; ++d) {
            bk  = fmaf(kbp[h * 16 + d], arel[(h * 16 + d) * 16 + f], bk);
            bvv = fmaf(vbp[h * 16 + d], mrel[(h * 16 + d) * 16 + f], bvv);
        }
        float* bp = bpack + l * 1408 + preB[si];
        bp[rowoff + hf]       = bk;
        bp[rowoff + 128 + hf] = bvv;
    }
}

__global__ __launch_bounds__(128) void prep_w9(
    const float* __restrict__ lin_w, const float* __restrict__ aw,
    unsigned short* __restrict__ lwt, unsigned short* __restrict__ awt)
{
    int n = threadIdx.x, k = blockIdx.x, mi = blockIdx.y;
    const float* w; unsigned short* wt; int m;
    if (mi < 3) { w = lin_w; wt = lwt; m = mi; }
    else        { w = aw;    wt = awt; m = mi - 3; }
    wt[(size_t)m * 16384 + (size_t)n * 128 + k] =
        f2bf(w[(size_t)m * 16384 + (size_t)k * 128 + n]);
}

__global__ __launch_bounds__(64) void prep_owt(
    const float* __restrict__ ow, unsigned short* __restrict__ owt)
{
    int n = threadIdx.x, k = blockIdx.x;
    owt[(size_t)n * 128 + k] = f2bf(ow[(size_t)k * 64 + n]);
}

// ------------------------- CSR build (fused across edge types) --------------
__global__ __launch_bounds__(256) void hist_all(
    const int* __restrict__ d0, const int* __restrict__ d1,
    const int* __restrict__ d2, const int* __restrict__ d3,
    int* __restrict__ deg4)
{
    const int Ev[4] = {200000, 300000, 200000, 100000};
    int et = blockIdx.y;
    int e = blockIdx.x * 256 + threadIdx.x;
    if (e >= Ev[et]) return;
    const int* d = et == 0 ? d0 : et == 1 ? d1 : et == 2 ? d2 : d3;
    atomicAdd(&deg4[et * 60000 + d[e]], 1);
}

__global__ __launch_bounds__(256) void scan_tile_all(
    const int* __restrict__ deg4,
    int* __restrict__ r0, int* __restrict__ r1, int* __restrict__ r2, int* __restrict__ r3,
    int* __restrict__ tsum4)
{
    const int Ndv[4] = {60000, 60000, 6000, 30000};
    __shared__ int ls[256];
    int et = blockIdx.y;
    int n = Ndv[et];
    const int* deg = deg4 + et * 60000;
    int* rowptr = et == 0 ? r0 : et == 1 ? r1 : et == 2 ? r2 : r3;
    int b = blockIdx.x, tid = threadIdx.x;
    int base = b * 1024 + tid * 4;
    int v0 = 0, v1 = 0, v2 = 0, v3 = 0;
    if (base + 3 < n) {
        int4 t = *(const int4*)(deg + base);
        v0 = t.x; v1 = t.y; v2 = t.z; v3 = t.w;
    } else {
        if (base + 0 < n) v0 = deg[base + 0];
        if (base + 1 < n) v1 = deg[base + 1];
        if (base + 2 < n) v2 = deg[base + 2];
        if (base + 3 < n) v3 = deg[base + 3];
    }
    int s = v0 + v1 + v2 + v3;
    ls[tid] = s;
    __syncthreads();
    #pragma unroll
    for (int off = 1; off < 256; off <<= 1) {
        int t = (tid >= off) ? ls[tid - off] : 0;
        __syncthreads();
        ls[tid] += t;
        __syncthreads();
    }
    int run = ls[tid] - s;
    int o0 = run; run += v0;
    int o1 = run; run += v1;
    int o2 = run; run += v2;
    int o3 = run;
    if (base + 3 < n) {
        *(int4*)(rowptr + base) = make_int4(o0, o1, o2, o3);
    } else {
        if (base + 0 < n) rowptr[base + 0] = o0;
        if (base + 1 < n) rowptr[base + 1] = o1;
        if (base + 2 < n) rowptr[base + 2] = o2;
    }
    if (tid == 255) tsum4[et * 64 + b] = ls[255];
}

__global__ __launch_bounds__(64) void scan_tsum_all(
    int* __restrict__ tsum4,
    int* __restrict__ r0, int* __restrict__ r1, int* __restrict__ r2, int* __restrict__ r3)
{
    const int Ndv[4] = {60000, 60000, 6000, 30000};
    int et = blockIdx.x;
    int n = Ndv[et];
    int nt = (n + 1023) >> 10;
    int* tileSum = tsum4 + et * 64;
    int* rowptr = et == 0 ? r0 : et == 1 ? r1 : et == 2 ? r2 : r3;
    int tid = threadIdx.x;
    int v = (tid < nt) ? tileSum[tid] : 0;
    int orig = v;
    #pragma unroll
    for (int off = 1; off < 64; off <<= 1) {
        int t = __shfl_up(v, off);
        if (tid >= off) v += t;
    }
    if (tid < nt) tileSum[tid] = v - orig;
    if (tid == nt - 1) rowptr[n] = v;
}

__global__ __launch_bounds__(256) void scan_add_all(
    int* __restrict__ r0, int* __restrict__ r1, int* __restrict__ r2, int* __restrict__ r3,
    const int* __restrict__ tsum4)
{
    const int Ndv[4] = {60000, 60000, 6000, 30000};
    int et = blockIdx.y;
    int n = Ndv[et];
    int* rowptr = et == 0 ? r0 : et == 1 ? r1 : et == 2 ? r2 : r3;
    int i = blockIdx.x * 256 + threadIdx.x;
    if (i < n) rowptr[i] += tsum4[et * 64 + (i >> 10)];
}

__global__ __launch_bounds__(256) void fill_all(
    const int* __restrict__ s0, const int* __restrict__ d0,
    const int* __restrict__ s1, const int* __restrict__ d1,
    const int* __restrict__ s2, const int* __restrict__ d2,
    const int* __restrict__ s3, const int* __restrict__ d3,
    const int* __restrict__ r0, const int* __restrict__ r1,
    const int* __restrict__ r2, const int* __restrict__ r3,
    int* __restrict__ deg4,
    int* __restrict__ c0, int* __restrict__ c1, int* __restrict__ c2, int* __restrict__ c3)
{
    const int Ev[4] = {200000, 300000, 200000, 100000};
    int et = blockIdx.y;
    int e = blockIdx.x * 256 + threadIdx.x;
    if (e >= Ev[et]) return;
    const int* src = et == 0 ? s0 : et == 1 ? s1 : et == 2 ? s2 : s3;
    const int* dst = et == 0 ? d0 : et == 1 ? d1 : et == 2 ? d2 : d3;
    const int* rowptr = et == 0 ? r0 : et == 1 ? r1 : et == 2 ? r2 : r3;
    int* csr = et == 0 ? c0 : et == 1 ? c1 : et == 2 ? c2 : c3;
    int d = dst[e];
    int pos = atomicAdd(&deg4[et * 60000 + d], 1);
    csr[rowptr[d] + pos] = src[e];
}

// --------------- merged gather-side attention (all 4 edge types) ------------
// Software-pipelined: edge j+1's K/V loads issue before edge j's compute.
// Defer-max (THR=8): o-rescale only when the running max grows by >8;
// exact math (o and l always carry the common factor exp(-m)).
__device__ __forceinline__ void attn_run(
    const int* __restrict__ csr, int beg, int end,
    const unsigned short* __restrict__ kbase, int ld,
    const float* qf, float ph, float& m, float& l, float* o)
{
    if (beg >= end) return;
    int s = csr[beg];
    const uint4* kp = (const uint4*)(kbase + (size_t)s * ld);
    uint4 ku0 = kp[0], ku1 = kp[1];
    uint4 vu0 = kp[16], vu1 = kp[17];       // mv at +128 shorts
    for (int j = beg; j < end; ++j) {
        uint4 nk0 = ku0, nk1 = ku1, nv0 = vu0, nv1 = vu1;
        if (j + 1 < end) {                  // prefetch next edge
            int sn = csr[j + 1];
            const uint4* np = (const uint4*)(kbase + (size_t)sn * ld);
            nk0 = np[0]; nk1 = np[1]; nv0 = np[16]; nv1 = np[17];
        }
        float kf[16], vf[16];
        up8(ku0, kf); up8(ku1, kf + 8);
        up8(vu0, vf); up8(vu1, vf + 8);
        float a = 0.f;
        #pragma unroll
        for (int i = 0; i < 16; ++i) a = fmaf(qf[i], kf[i], a);
        a *= ph;
        float d = a - m;
        if (d > 8.f) {                      // rare after first edge
            float sc = __expf(-d);
            l *= sc;
            #pragma unroll
            for (int i = 0; i < 16; ++i) o[i] *= sc;
            m = a; d = 0.f;
        }
        float w = __expf(d);                // d <= 8 -> w <= e^8
        l += w;
        #pragma unroll
        for (int i = 0; i < 16; ++i) o[i] = fmaf(w, vf[i], o[i]);
        ku0 = nk0; ku1 = nk1; vu0 = nv0; vu1 = nv1;
    }
}

// grid: [0,1875) road(et0+et1 serial) / [1875,2625) region(et2, 4-way split) /
//       [2625,3563) poi(et3)
__global__ __launch_bounds__(256) void agg_all(
    const int* __restrict__ rp0, const int* __restrict__ cs0,
    const int* __restrict__ rp1, const int* __restrict__ cs1,
    const int* __restrict__ rp2, const int* __restrict__ cs2,
    const int* __restrict__ rp3, const int* __restrict__ cs3,
    const unsigned short* __restrict__ P0, const unsigned short* __restrict__ P1,
    const unsigned short* __restrict__ P2,
    const float* __restrict__ prl,      // p_rel + l*32
    unsigned short* __restrict__ num)
{
    int gb = blockIdx.x, tid = threadIdx.x;
    float qf[16], o[16], r[16];
    if (gb < 1875) {
        // ---- road: et0 (poi src) + et1 (road src), separate softmaxes ----
        int t = gb * 256 + tid;            // < 480000 exactly
        int node = t >> 3, h = t & 7;
        const uint4* qp = (const uint4*)(P1 + (size_t)node * 640 + h * 16);
        up8(qp[0], qf); up8(qp[1], qf + 8);
        float m0 = -INFINITY, l0 = 0.f;
        #pragma unroll
        for (int i = 0; i < 16; ++i) o[i] = 0.f;
        attn_run(cs0, rp0[node], rp0[node + 1], P0 + 128 + h * 16, 384,
                 qf, prl[h] * 0.25f, m0, l0, o);
        float i0 = 1.f / (l0 + 1e-16f);
        #pragma unroll
        for (int i = 0; i < 16; ++i) { r[i] = i0 * o[i]; o[i] = 0.f; }
        float m1 = -INFINITY, l1 = 0.f;
        attn_run(cs1, rp1[node], rp1[node + 1], P1 + 128 + h * 16, 640,
                 qf, prl[8 + h] * 0.25f, m1, l1, o);
        float i1 = 1.f / (l1 + 1e-16f);
        #pragma unroll
        for (int i = 0; i < 16; ++i) r[i] += i1 * o[i];
        uint4* np = (uint4*)(num + (size_t)(30000 + node) * 128 + h * 16);
        np[0] = pk8(r); np[1] = pk8(r + 8);
    } else if (gb < 2625) {
        // ---- region: et2 (road src), 4-way edge split + shuffle merge ----
        int t = (gb - 1875) * 256 + tid;   // < 192000 exactly
        int node = t >> 5, h = t & 7, sub = (t >> 3) & 3;
        int beg0 = rp2[node], end0 = rp2[node + 1];
        int n = end0 - beg0;
        int beg = beg0 + ((n * sub) >> 2);
        int end = beg0 + ((n * (sub + 1)) >> 2);
        const uint4* qp = (const uint4*)(P2 + (size_t)node * 384 + h * 16);
        up8(qp[0], qf); up8(qp[1], qf + 8);
        float m = -INFINITY, l = 0.f;
        #pragma unroll
        for (int i = 0; i < 16; ++i) o[i] = 0.f;
        attn_run(cs2, beg, end, P1 + 384 + h * 16, 640,
                 qf, prl[16 + h] * 0.25f, m, l, o);
        #pragma unroll
        for (int st = 8; st <= 16; st <<= 1) {
            float mp = __shfl_xor(m, st);
            float lp = __shfl_xor(l, st);
            float mn = fmaxf(m, mp);
            float sc  = (l  > 0.f) ? __expf(m  - mn) : 0.f;
            float scp = (lp > 0.f) ? __expf(mp - mn) : 0.f;
            l = l * sc + lp * scp;
            #pragma unroll
            for (int i = 0; i < 16; ++i) {
                float op = __shfl_xor(o[i], st);
                o[i] = o[i] * sc + op * scp;
            }
            m = mn;
        }
        if (sub) return;
        float inv = 1.f / (l + 1e-16f);
        #pragma unroll
        for (int i = 0; i < 16; ++i) r[i] = inv * o[i];
        uint4* np = (uint4*)(num + (size_t)(90000 + node) * 128 + h * 16);
        np[0] = pk8(r); np[1] = pk8(r + 8);
    } else {
        // ---- poi: et3 (region src) ----
        int t = (gb - 2625) * 256 + tid;
        if (t >= 240000) return;
        int node = t >> 3, h = t & 7;
        const uint4* qp = (const uint4*)(P0 + (size_t)node * 384 + h * 16);
        up8(qp[0], qf); up8(qp[1], qf + 8);
        float m = -INFINITY, l = 0.f;
        #pragma unroll
        for (int i = 0; i < 16; ++i) o[i] = 0.f;
        attn_run(cs3, rp3[node], rp3[node + 1], P2 + 128 + h * 16, 384,
                 qf, prl[24 + h] * 0.25f, m, l, o);
        float inv = 1.f / (l + 1e-16f);
        #pragma unroll
        for (int i = 0; i < 16; ++i) r[i] = inv * o[i];
        uint4* np = (uint4*)(num + (size_t)node * 128 + h * 16);
        np[0] = pk8(r); np[1] = pk8(r + 8);
    }
}

extern "C" void kernel_launch(void* const* d_in, const int* in_sizes, int n_in,
                              void* d_out, int out_size, void* d_ws, size_t ws_size,
                              hipStream_t stream)
{
    (void)in_sizes; (void)n_in; (void)out_size; (void)ws_size;

    const float* xin[3] = {(const float*)d_in[0], (const float*)d_in[1], (const float*)d_in[2]};
    const int* esrc[4] = {(const int*)d_in[3], (const int*)d_in[5], (const int*)d_in[7], (const int*)d_in[9]};
    const int* edst[4] = {(const int*)d_in[4], (const int*)d_in[6], (const int*)d_in[8], (const int*)d_in[10]};
    const float* lin_w = (const float*)d_in[11];
    const float* lin_b = (const float*)d_in[12];
    const float* kw = (const float*)d_in[13];
    const float* qw = (const float*)d_in[14];
    const float* vw = (const float*)d_in[15];
    const float* aw = (const float*)d_in[16];
    const float* kb = (const float*)d_in[17];
    const float* qb = (const float*)d_in[18];
    const float* vb = (const float*)d_in[19];
    const float* ab = (const float*)d_in[20];
    const float* a_rel = (const float*)d_in[21];
    const float* m_rel = (const float*)d_in[22];
    const float* p_rel = (const float*)d_in[23];
    const float* skip  = (const float*)d_in[24];
    const float* out_w = (const float*)d_in[25];
    const float* out_b = (const float*)d_in[26];

    // workspace (float-index units; ~39.9M floats = 160 MB)
    float* ws = (float*)d_ws;
    unsigned short* num   = (unsigned short*)ws;                // 12,288,000 h
    unsigned short* xs_bf = (unsigned short*)(ws + 6144000);    // 12,288,000 h
    unsigned short* proj  = (unsigned short*)(ws + 12288000);   // 52,224,000 h
    unsigned short* Wpack = (unsigned short*)(ws + 38400000);   // 360,448 h
    unsigned short* lwt   = (unsigned short*)(ws + 38580224);   // 49,152 h
    unsigned short* awt   = (unsigned short*)(ws + 38604800);   // 98,304 h
    unsigned short* owt   = (unsigned short*)(ws + 38653952);   // 8,192 h
    float*          bpack = ws + 38658048;                      // 2,816 f
    int*            deg4  = (int*)(ws + 38660864);              // 240,000
    int*            tsum4 = (int*)(ws + 38900864);              // 256
    int* rp[4];
    rp[0] = (int*)(ws + 38901120);                              // 60,008
    rp[1] = (int*)(ws + 38961128);
    rp[2] = (int*)(ws + 39021136);                              // 6,008
    rp[3] = (int*)(ws + 39027144);                              // 30,008
    int* cs[4];
    cs[0] = (int*)(ws + 39057152);                              // 200,000
    cs[1] = (int*)(ws + 39257152);                              // 300,000
    cs[2] = (int*)(ws + 39557152);                              // 200,000
    cs[3] = (int*)(ws + 39757152);                              // 100,000

    unsigned short* P[3];
    P[0] = proj;
    P[1] = proj + (size_t)30000 * 384;
    P[2] = proj + (size_t)30000 * 384 + (size_t)60000 * 640;

    dim3 blk(256);

    // ---- CSR build, fused across edge types ----
    hipMemsetAsync(deg4, 0, 960000, stream);
    hist_all<<<dim3(1172, 4), blk, 0, stream>>>(edst[0], edst[1], edst[2], edst[3], deg4);
    scan_tile_all<<<dim3(59, 4), blk, 0, stream>>>(deg4, rp[0], rp[1], rp[2], rp[3], tsum4);
    scan_tsum_all<<<dim3(4), dim3(64), 0, stream>>>(tsum4, rp[0], rp[1], rp[2], rp[3]);
    scan_add_all<<<dim3(235, 4), blk, 0, stream>>>(rp[0], rp[1], rp[2], rp[3], tsum4);
    hipMemsetAsync(deg4, 0, 960000, stream);
    fill_all<<<dim3(1172, 4), blk, 0, stream>>>(
        esrc[0], edst[0], esrc[1], edst[1], esrc[2], edst[2], esrc[3], edst[3],
        rp[0], rp[1], rp[2], rp[3], deg4, cs[0], cs[1], cs[2], cs[3]);

    // ---- weight prep ----
    prep_qpack<<<dim3(128, 3, 2), dim3(128), 0, stream>>>(qw, qb, Wpack, bpack);
    fold_rel_pack<<<dim3(128, 4, 2), dim3(128), 0, stream>>>(
        kw, kb, vw, vb, a_rel, m_rel, Wpack, bpack);
    prep_w9<<<dim3(128, 9), dim3(128), 0, stream>>>(lin_w, aw, lwt, awt);
    prep_owt<<<dim3(128), dim3(64), 0, stream>>>(out_w, owt);

    // ---- input linear + relu -> xs_bf (fused across types) ----
    gemm_node<true, false, false><<<dim3(751), blk, 0, stream>>>(
        xin[0], xin[1], xin[2], lwt, lin_b, nullptr, nullptr, xs_bf);

    for (int l = 0; l < 2; ++l) {
        // packed projection per node type: [q | ka|mv ...], one fused launch
        gemm_proj_all<<<dim3(803), blk, 0, stream>>>(
            xs_bf, Wpack + (size_t)l * 180224, bpack + l * 1408, proj);

        // merged aggregation: all 4 edge types in one launch
        agg_all<<<dim3(3563), blk, 0, stream>>>(
            rp[0], cs[0], rp[1], cs[1], rp[2], cs[2], rp[3], cs[3],
            P[0], P[1], P[2], p_rel + (size_t)l * 32, num);

        // node update (fused across types)
        gemm_node<false, true, true><<<dim3(751), blk, 0, stream>>>(
            num, num + (size_t)30000 * 128, num + (size_t)90000 * 128,
            awt + (size_t)l * 3 * 16384, ab + (size_t)l * 3 * 128,
            xs_bf, skip + l * 3, xs_bf);
    }

    // ---- output projection: single GEMM over all 96000 rows ----
    gemm_out<<<dim3(375), blk, 0, stream>>>(
        xs_bf, owt, out_b, (float*)d_out, 96000);
}